// Round 13
// baseline (265.200 us; speedup 1.0000x reference)
//
#include <hip/hip_runtime.h>
#include <hip/hip_bf16.h>
#include <math.h>

#define DI __device__ __forceinline__

typedef __attribute__((ext_vector_type(8))) __bf16 bf16x8;
typedef __attribute__((ext_vector_type(8))) short short8;
typedef __attribute__((ext_vector_type(4))) float f32x4;
typedef __attribute__((ext_vector_type(4))) int int4v;
typedef __attribute__((ext_vector_type(4))) unsigned short ushort4v;

// native RTNE f32->bf16 (v_cvt_pk_bf16_f32 on gfx950)
DI short f2bfn(float f) {
  __bf16 b = (__bf16)f;
  short s;
  __builtin_memcpy(&s, &b, 2);
  return s;
}

DI void gload_lds16(const void* g, void* l) {
  __builtin_amdgcn_global_load_lds(
      (const __attribute__((address_space(1))) void*)g,
      (__attribute__((address_space(3))) void*)l, 16, 0, 0);
}

// ---------------- weight transpose + fp32->bf16 convert ----------------
__global__ __launch_bounds__(256) void transpose_cvt(
    const float* __restrict__ in, short* __restrict__ out, int K, int N)
{
  __shared__ float tile[32][33];
  const int tx = threadIdx.x & 31, ty = threadIdx.x >> 5;
  const int n0 = blockIdx.x * 32, k0 = blockIdx.y * 32;
#pragma unroll
  for (int p = 0; p < 4; ++p)
    tile[ty + p * 8][tx] = in[(size_t)(k0 + ty + p * 8) * N + n0 + tx];
  __syncthreads();
#pragma unroll
  for (int p = 0; p < 4; ++p)
    out[(size_t)(n0 + ty + p * 8) * K + k0 + tx] = f2bfn(tile[tx][ty + p * 8]);
}

// ---------------- V transpose: vT[(b*8+h)*96 + d][n] = V[b][n][h*96+d] ----
__global__ __launch_bounds__(256) void v_transpose(
    const short* __restrict__ qkv, short* __restrict__ vT)
{
  __shared__ short tile[64][98];
  const int t = threadIdx.x;
  const int bh = blockIdx.x, nt = blockIdx.y;
  const int b = bh >> 3, h = bh & 7;
  const size_t gbase = (size_t)(b * 1024 + nt * 64) * 2304 + 1536 + h * 96;
#pragma unroll
  for (int i = 0; i < 3; ++i) {
    const int p = i * 256 + t;
    const int row = p / 12, cb = p % 12;
    const short8 v = *(const short8*)(qkv + gbase + (size_t)row * 2304 + cb * 8);
#pragma unroll
    for (int j = 0; j < 4; ++j) {
      unsigned pk = (unsigned)(unsigned short)v[2 * j] |
                    ((unsigned)(unsigned short)v[2 * j + 1] << 16);
      *(unsigned*)&tile[row][cb * 8 + 2 * j] = pk;
    }
  }
  __syncthreads();
#pragma unroll
  for (int i = 0; i < 3; ++i) {
    const int p = i * 256 + t;
    const int d = p >> 3, cb = p & 7;
    short8 o;
#pragma unroll
    for (int j = 0; j < 8; ++j) o[j] = tile[cb * 8 + j][d];
    *(short8*)(vT + ((size_t)bh * 96 + d) * 1024 + nt * 64 + cb * 8) = o;
  }
}

// ---------------- layernorm: 1 wave per row of 768, fp32 in, bf16 out ----
__global__ __launch_bounds__(256) void ln_rows(
    const float* __restrict__ x, const float* __restrict__ gw,
    const float* __restrict__ bw, unsigned short* __restrict__ out)
{
  const int wv = threadIdx.x >> 6, ln = threadIdx.x & 63;
  const size_t row = (size_t)blockIdx.x * 4 + wv;
  const float* xr = x + row * 768;
  float4 v[3];
  float s = 0.f, sq = 0.f;
#pragma unroll
  for (int i = 0; i < 3; ++i) {
    v[i] = *(const float4*)(xr + i * 256 + ln * 4);
    s  += v[i].x + v[i].y + v[i].z + v[i].w;
    sq += v[i].x * v[i].x + v[i].y * v[i].y + v[i].z * v[i].z + v[i].w * v[i].w;
  }
#pragma unroll
  for (int msk = 1; msk < 64; msk <<= 1) {
    s  += __shfl_xor(s, msk);
    sq += __shfl_xor(sq, msk);
  }
  const float mean = s * (1.f / 768.f);
  const float var  = sq * (1.f / 768.f) - mean * mean;
  const float rstd = rsqrtf(var + 1e-5f);
#pragma unroll
  for (int i = 0; i < 3; ++i) {
    const int c = i * 256 + ln * 4;
    const float vals[4] = {v[i].x, v[i].y, v[i].z, v[i].w};
    ushort4v o;
#pragma unroll
    for (int j = 0; j < 4; ++j)
      o[j] = (unsigned short)f2bfn((vals[j] - mean) * rstd * gw[c + j] + bw[c + j]);
    *(ushort4v*)(out + row * 768 + c) = o;
  }
}

// ---------------- GEMM v5: C[M,N] = A[M,K] * Bt[N,K]^T + epilogue ---------
// Per K-step: [vmcnt(LOADS)+barrierA] -> frag reads + MFMAs (compiler
// interleaves with fine lgkmcnt) -> [lgkmcnt(0)+barrierB] -> stage(kt+2).
// Counted vmcnt (T4): loads retire in order, so vmcnt(LOADS) proves
// stage(kt) landed while stage(kt+1)/(kt+2) stay in flight. Both-sides
// chunk-XOR swizzle (rule #21). LDS-bounce epilogue.
enum { EPI_BF16 = 0, EPI_F32_RES = 1, EPI_BF16_GELU = 2, EPI_F32 = 3 };
#define EPITCH 132

template <int MODE, int BM, int BK, int MW>
__global__ __launch_bounds__(256, MW) void gemm_bt(
    const short* __restrict__ A,    // pitch = K
    const short* __restrict__ Bt,   // pitch = K
    const float* __restrict__ bias,
    const float* __restrict__ resid,  // pitch = ldc (fp32) when used
    void* __restrict__ Cout, int ldc,
    int Ntiles, int K)
{
  constexpr int NCHUNK = BK / 8;
  constexpr int CMASK = NCHUNK - 1;
  constexpr int ABYTES = BM * BK * 2;
  constexpr int STAGE_BYTES = (BM + 128) * BK * 2;
  constexpr int NLA = BM * BK / 8 / 256;
  constexpr int NLB = 128 * BK / 8 / 256;
  constexpr int LOADS = NLA + NLB;
  constexpr int MR = BM / 32;
  constexpr int NKK = BK / 32;
  constexpr int SMEM = 2 * STAGE_BYTES > 32 * EPITCH * 4 ? 2 * STAGE_BYTES
                                                         : 32 * EPITCH * 4;
  __shared__ __align__(16) char smem[SMEM];
  const int t = threadIdx.x;
  const int wv = t >> 6, ln = t & 63;
  const int g = ln >> 4, r = ln & 15;
  const int sw = ((int)blockIdx.x & 7) * ((int)gridDim.x >> 3) + ((int)blockIdx.x >> 3);
  const int bm = sw / Ntiles, bn = sw % Ntiles;
  const int wr = wv >> 1, wc = wv & 1;
  f32x4 acc[MR][4] = {};

  // staging source pointers (pre-swizzled), advanced by BK elems per stage
  const char* aptr[NLA];
  const char* bptr[NLB];
#pragma unroll
  for (int q = 0; q < NLA; ++q) {
    const int p = q * 256 + t;
    const int row = p / NCHUNK, c = (p & CMASK) ^ (row & CMASK);
    aptr[q] = (const char*)(A + (size_t)(bm * BM + row) * K + c * 8);
  }
#pragma unroll
  for (int q = 0; q < NLB; ++q) {
    const int p = q * 256 + t;
    const int row = p / NCHUNK, c = (p & CMASK) ^ (row & CMASK);
    bptr[q] = (const char*)(Bt + (size_t)(bn * 128 + row) * K + c * 8);
  }

  auto stage = [&](int buf) {
    char* as = smem + buf * STAGE_BYTES;
    char* bs = as + ABYTES;
#pragma unroll
    for (int q = 0; q < NLA; ++q) {
      gload_lds16(aptr[q], as + q * 4096 + wv * 1024);
      aptr[q] += BK * 2;
    }
#pragma unroll
    for (int q = 0; q < NLB; ++q) {
      gload_lds16(bptr[q], bs + q * 4096 + wv * 1024);
      bptr[q] += BK * 2;
    }
  };

  const int nk = K / BK;
  stage(0);
  stage(1);
  int cur = 0;
  for (int kt = 0; kt < nk; ++kt) {
    // barrier A: my stage(kt) landed (in-order retire) + all waves ditto
    if (kt + 1 < nk)
      asm volatile("s_waitcnt vmcnt(%0)\n\ts_barrier" :: "n"(LOADS) : "memory");
    else
      asm volatile("s_waitcnt vmcnt(0)\n\ts_barrier" ::: "memory");
    const short* as = (const short*)(smem + cur * STAGE_BYTES);
    const short* bs = as + ABYTES / 2;
    bf16x8 af[MR][NKK], bfr[4][NKK];
#pragma unroll
    for (int m = 0; m < MR; ++m) {
      const int row = wr * (BM / 2) + m * 16 + r;
#pragma unroll
      for (int kk = 0; kk < NKK; ++kk)
        af[m][kk] = *(const bf16x8*)(as + row * BK + (((kk * 4 + g) ^ (row & CMASK)) << 3));
    }
#pragma unroll
    for (int n = 0; n < 4; ++n) {
      const int row = wc * 64 + n * 16 + r;
#pragma unroll
      for (int kk = 0; kk < NKK; ++kk)
        bfr[n][kk] = *(const bf16x8*)(bs + row * BK + (((kk * 4 + g) ^ (row & CMASK)) << 3));
    }
    // MFMAs: compiler interleaves with the ds_reads via partial lgkmcnt
#pragma unroll
    for (int kk = 0; kk < NKK; ++kk)
#pragma unroll
      for (int m = 0; m < MR; ++m)
#pragma unroll
        for (int n = 0; n < 4; ++n)
          acc[m][n] = __builtin_amdgcn_mfma_f32_16x16x32_bf16(af[m][kk], bfr[n][kk],
                                                              acc[m][n], 0, 0, 0);
    if (kt + 2 < nk) {
      // barrier B: my reads complete + all waves done reading buf[cur]
      asm volatile("s_waitcnt lgkmcnt(0)\n\ts_barrier" ::: "memory");
      stage(cur);  // overwrite freed buffer (lands by body kt+2's barrier A)
    }
    cur ^= 1;
  }
  __syncthreads();  // full drain before epilogue reuses smem

  // ---- epilogue: LDS bounce, coalesced stores ----
  float* epi = (float*)smem;
  const int cq = (t & 7) * 16;
  const int c0 = bn * 128 + cq;
  f32x4 bv[4];
#pragma unroll
  for (int j = 0; j < 4; ++j) bv[j] = *(const f32x4*)(bias + c0 + j * 4);

#pragma unroll
  for (int m = 0; m < MR; ++m) {
#pragma unroll
    for (int n = 0; n < 4; ++n) {
      const int col = wc * 64 + n * 16 + r;
#pragma unroll
      for (int q = 0; q < 4; ++q)
        epi[(wr * 16 + g * 4 + q) * EPITCH + col] = acc[m][n][q];
    }
    __syncthreads();
    const int lr = t >> 3;
    const size_t grow = (size_t)(bm * BM + (lr < 16 ? m * 16 + lr
                                                    : BM / 2 + m * 16 + (lr - 16)));
    float vals[16];
#pragma unroll
    for (int j = 0; j < 4; ++j) {
      const f32x4 vv = *(const f32x4*)(epi + lr * EPITCH + cq + j * 4);
#pragma unroll
      for (int e = 0; e < 4; ++e) vals[j * 4 + e] = vv[e] + bv[j][e];
    }
    if constexpr (MODE == EPI_F32_RES) {
#pragma unroll
      for (int j = 0; j < 4; ++j) {
        const f32x4 rv = *(const f32x4*)(resid + grow * ldc + c0 + j * 4);
#pragma unroll
        for (int e = 0; e < 4; ++e) vals[j * 4 + e] += rv[e];
      }
    }
    if constexpr (MODE == EPI_BF16_GELU) {
#pragma unroll
      for (int j = 0; j < 16; ++j)
        vals[j] = 0.5f * vals[j] * (1.0f + erff(vals[j] * 0.70710678118654752f));
    }
    if constexpr (MODE == EPI_F32 || MODE == EPI_F32_RES) {
      float* op = (float*)Cout + grow * ldc + c0;
#pragma unroll
      for (int j = 0; j < 4; ++j) {
        f32x4 ov;
#pragma unroll
        for (int e = 0; e < 4; ++e) ov[e] = vals[j * 4 + e];
        *(f32x4*)(op + j * 4) = ov;
      }
    } else {
      unsigned short* op = (unsigned short*)Cout + grow * ldc + c0;
#pragma unroll
      for (int hhalf = 0; hhalf < 2; ++hhalf) {
        short8 ov;
#pragma unroll
        for (int e = 0; e < 8; ++e) ov[e] = f2bfn(vals[hhalf * 8 + e]);
        *(short8*)(op + hhalf * 8) = ov;
      }
    }
    __syncthreads();
  }
}

// ---------------- flash attention v6: swapped QK^T (lane-major softmax) --
// (unchanged from round 10)
__global__ __launch_bounds__(256, 2) void attn_fwd(
    const short* __restrict__ qkv, const short* __restrict__ vT,
    unsigned short* __restrict__ ab)
{
  __shared__ short Ks[2][64 * 128];    // 32 KB
  __shared__ short Vs[2][96 * 64];     // 24 KB
  __shared__ short Ps[4][2][16 * 64];  // 16 KB
  const int t = threadIdx.x, wv = t >> 6, ln = t & 63;
  const int g = ln >> 4, r = ln & 15;
  const int bid = ((int)blockIdx.x & 7) * 64 + ((int)blockIdx.x >> 3);
  const int bh = bid >> 3, qt = bid & 7;
  const int b = bh >> 3, h = bh & 7;

  bf16x8 qf[2][3];
#pragma unroll
  for (int u = 0; u < 2; ++u) {
    const size_t rowq = (size_t)(b * 1024 + qt * 128 + wv * 32 + u * 16 + r);
#pragma unroll
    for (int kd = 0; kd < 3; ++kd)
      qf[u][kd] = *(const bf16x8*)(qkv + rowq * 2304 + h * 96 + kd * 32 + g * 8);
  }

  size_t offK[4];
#pragma unroll
  for (int i = 0; i < 4; ++i) {
    const int p = i * 256 + t;
    const int row = p >> 4, cb = p & 15, cbs = cb ^ (row & 7);
    offK[i] = (size_t)row * 2304 + 768 + h * 96 + (cbs << 3);
  }
  size_t offV[3];
#pragma unroll
  for (int i = 0; i < 3; ++i) {
    const int p = i * 256 + t;
    const int row = p >> 3, cb = p & 7, cbs = cb ^ (row & 7);
    offV[i] = ((size_t)bh * 96 + row) * 1024 + (cbs << 3);
  }
  const short* qb = qkv + (size_t)b * 1024 * 2304;

  auto stageKV = [&](int buf, int kt) {
    const size_t kadd = (size_t)kt * 64 * 2304;
#pragma unroll
    for (int i = 0; i < 4; ++i)
      gload_lds16(qb + kadd + offK[i], (char*)Ks[buf] + i * 4096 + wv * 1024);
#pragma unroll
    for (int i = 0; i < 3; ++i)
      gload_lds16(vT + offV[i] + kt * 64, (char*)Vs[buf] + i * 4096 + wv * 1024);
  };

  f32x4 o[2][6] = {};
  float mr[2] = {-1e30f, -1e30f}, lr[2] = {0.f, 0.f};  // stats for q-row r

  stageKV(0, 0);
  __syncthreads();
  int cur = 0;
  for (int kt = 0; kt < 16; ++kt) {
    if (kt < 15) stageKV(cur ^ 1, kt + 1);
    const short* ks = Ks[cur];
    const short* vs = Vs[cur];

    // ---- S^T = K Q^T for BOTH u, sharing each kf fragment ----
    f32x4 s[2][4] = {};
    __builtin_amdgcn_s_setprio(1);
#pragma unroll
    for (int sub = 0; sub < 4; ++sub) {
      bf16x8 kf[3];
#pragma unroll
      for (int kd = 0; kd < 3; ++kd)
        kf[kd] = *(const bf16x8*)(
            ks + (sub * 16 + r) * 128 + (((kd * 4 + g) ^ (r & 7)) << 3));
#pragma unroll
      for (int u = 0; u < 2; ++u)
#pragma unroll
        for (int kd = 0; kd < 3; ++kd)
          s[u][sub] = __builtin_amdgcn_mfma_f32_16x16x32_bf16(kf[kd], qf[u][kd],
                                                              s[u][sub], 0, 0, 0);
    }
    __builtin_amdgcn_s_setprio(0);

    // ---- lane-major online softmax per u ----
#pragma unroll
    for (int u = 0; u < 2; ++u) {
      float tm = fmaxf(fmaxf(s[u][0][0], s[u][0][1]),
                       fmaxf(s[u][0][2], s[u][0][3]));
#pragma unroll
      for (int sub = 1; sub < 4; ++sub)
        tm = fmaxf(tm, fmaxf(fmaxf(s[u][sub][0], s[u][sub][1]),
                             fmaxf(s[u][sub][2], s[u][sub][3])));
      tm = fmaxf(tm, __shfl_xor(tm, 16));
      tm = fmaxf(tm, __shfl_xor(tm, 32));

      if (__any(tm > mr[u] + 8.f)) {   // defer-max: rescale rarely
        const float mnew = fmaxf(mr[u], tm);
        const float sc = __expf(mr[u] - mnew);
        lr[u] *= sc;
        mr[u] = mnew;
        float scr[4];
#pragma unroll
        for (int reg = 0; reg < 4; ++reg)
          scr[reg] = __shfl(sc, (ln & 48) | (g * 4 + reg));
#pragma unroll
        for (int nd = 0; nd < 6; ++nd)
#pragma unroll
          for (int reg = 0; reg < 4; ++reg) o[u][nd][reg] *= scr[reg];
      }

      float tsum = 0.f;
#pragma unroll
      for (int sub = 0; sub < 4; ++sub) {
        float p0 = __expf(s[u][sub][0] - mr[u]);
        float p1 = __expf(s[u][sub][1] - mr[u]);
        float p2 = __expf(s[u][sub][2] - mr[u]);
        float p3 = __expf(s[u][sub][3] - mr[u]);
        tsum += (p0 + p1) + (p2 + p3);
        ushort4v pk;
        pk[0] = (unsigned short)f2bfn(p0);
        pk[1] = (unsigned short)f2bfn(p1);
        pk[2] = (unsigned short)f2bfn(p2);
        pk[3] = (unsigned short)f2bfn(p3);
        const int c8 = (sub * 4 + g) ^ ((r & 7) << 1);
        *(ushort4v*)((char*)Ps[wv][u] + r * 128 + c8 * 8) = pk;
      }
      tsum += __shfl_xor(tsum, 16);
      tsum += __shfl_xor(tsum, 32);
      lr[u] += tsum;
    }

    // ---- O += P V for BOTH u, sharing each vf fragment ----
    bf16x8 pf[2][2];
#pragma unroll
    for (int u = 0; u < 2; ++u)
#pragma unroll
      for (int kk = 0; kk < 2; ++kk)
        pf[u][kk] = *(const bf16x8*)(
            Ps[wv][u] + r * 64 + (((kk * 4 + g) ^ (r & 7)) << 3));
    __builtin_amdgcn_s_setprio(1);
#pragma unroll
    for (int nd = 0; nd < 6; ++nd) {
      bf16x8 vf[2];
#pragma unroll
      for (int kk = 0; kk < 2; ++kk)
        vf[kk] = *(const bf16x8*)(
            vs + (nd * 16 + r) * 64 + (((kk * 4 + g) ^ (r & 7)) << 3));
#pragma unroll
      for (int u = 0; u < 2; ++u)
#pragma unroll
        for (int kk = 0; kk < 2; ++kk)
          o[u][nd] = __builtin_amdgcn_mfma_f32_16x16x32_bf16(pf[u][kk], vf[kk],
                                                             o[u][nd], 0, 0, 0);
    }
    __builtin_amdgcn_s_setprio(0);

    __syncthreads();  // drains stage(kt+1); frees cur for rewrite
    cur ^= 1;
  }

  // epilogue: O * (96 / l); l for o-row g*4+reg fetched from lane r'=row
#pragma unroll
  for (int u = 0; u < 2; ++u) {
    float linv[4];
#pragma unroll
    for (int reg = 0; reg < 4; ++reg)
      linv[reg] = 96.0f / __shfl(lr[u], (ln & 48) | (g * 4 + reg));
#pragma unroll
    for (int reg = 0; reg < 4; ++reg) {
      const size_t row = (size_t)(b * 1024 + qt * 128 + wv * 32 + u * 16 + g * 4 + reg);
#pragma unroll
      for (int nd = 0; nd < 6; ++nd)
        ab[row * 768 + h * 96 + nd * 16 + r] =
            (unsigned short)f2bfn(o[u][nd][reg] * linv[reg]);
    }
  }
}

// ------------------------------------------------------------------------
extern "C" void kernel_launch(void* const* d_in, const int* in_sizes, int n_in,
                              void* d_out, int out_size, void* d_ws, size_t ws_size,
                              hipStream_t stream)
{
  const float* x    = (const float*)d_in[0];
  const float* ln1g = (const float*)d_in[1];
  const float* ln1b = (const float*)d_in[2];
  const float* Wq   = (const float*)d_in[3];
  const float* bq   = (const float*)d_in[4];
  const float* Wk   = (const float*)d_in[5];
  const float* bk   = (const float*)d_in[6];
  const float* Wv   = (const float*)d_in[7];
  const float* bv   = (const float*)d_in[8];
  const float* Wo   = (const float*)d_in[9];
  const float* bo   = (const float*)d_in[10];
  const float* ln2g = (const float*)d_in[11];
  const float* ln2b = (const float*)d_in[12];
  const float* W1   = (const float*)d_in[13];
  const float* b1   = (const float*)d_in[14];
  const float* W2   = (const float*)d_in[15];
  const float* b2   = (const float*)d_in[16];

  char* ws = (char*)d_ws;
  size_t off = 0;
  short* Wtqkv = (short*)(ws + off); off += (size_t)2304 * 768 * 2;
  short* Wto   = (short*)(ws + off); off += (size_t)768 * 768 * 2;
  short* Wt1   = (short*)(ws + off); off += (size_t)3072 * 768 * 2;
  short* Wt2   = (short*)(ws + off); off += (size_t)768 * 3072 * 2;
  float* bqkv  = (float*)(ws + off); off += 16384;
  short* hb    = (short*)(ws + off); off += (size_t)8192 * 768 * 2;
  short* qkv   = (short*)(ws + off); off += (size_t)8192 * 2304 * 2;
  short* h2b   = (short*)(ws + off); off += (size_t)8192 * 768 * 2;
  short* f1 = hb;          // [8192][3072] bf16, overlays hb+qkv (both dead)
  short* ab = hb;          // attention output overlays hb
  short* vT = h2b;         // V^T [64*96][1024], overlays h2b
  float* x1 = (float*)d_out;  // residual stream parked in d_out

  transpose_cvt<<<dim3(24, 24), 256, 0, stream>>>(Wq, Wtqkv, 768, 768);
  transpose_cvt<<<dim3(24, 24), 256, 0, stream>>>(Wk, Wtqkv + (size_t)768 * 768, 768, 768);
  transpose_cvt<<<dim3(24, 24), 256, 0, stream>>>(Wv, Wtqkv + (size_t)1536 * 768, 768, 768);
  transpose_cvt<<<dim3(24, 24), 256, 0, stream>>>(Wo, Wto, 768, 768);
  transpose_cvt<<<dim3(96, 24), 256, 0, stream>>>(W1, Wt1, 768, 3072);
  transpose_cvt<<<dim3(24, 96), 256, 0, stream>>>(W2, Wt2, 3072, 768);
  hipMemcpyAsync(bqkv,        bq, 768 * sizeof(float), hipMemcpyDeviceToDevice, stream);
  hipMemcpyAsync(bqkv + 768,  bk, 768 * sizeof(float), hipMemcpyDeviceToDevice, stream);
  hipMemcpyAsync(bqkv + 1536, bv, 768 * sizeof(float), hipMemcpyDeviceToDevice, stream);

  ln_rows<<<2048, 256, 0, stream>>>(x, ln1g, ln1b, (unsigned short*)hb);
  gemm_bt<EPI_BF16, 128, 32, 4><<<64 * 18, 256, 0, stream>>>(hb, Wtqkv, bqkv, nullptr, qkv, 2304, 18, 768);
  v_transpose<<<dim3(64, 16), 256, 0, stream>>>(qkv, vT);
  attn_fwd<<<512, 256, 0, stream>>>(qkv, vT, (unsigned short*)ab);
  gemm_bt<EPI_F32_RES, 64, 64, 3><<<128 * 6, 256, 0, stream>>>(ab, Wto, bo, x, x1, 768, 6, 768);

  ln_rows<<<2048, 256, 0, stream>>>(x1, ln2g, ln2b, (unsigned short*)h2b);
  gemm_bt<EPI_BF16_GELU, 128, 32, 4><<<64 * 24, 256, 0, stream>>>(h2b, Wt1, b1, nullptr, f1, 3072, 24, 768);
  gemm_bt<EPI_F32, 64, 64, 3><<<128 * 6, 256, 0, stream>>>(f1, Wt2, b2, nullptr, (float*)d_out, 768, 6, 3072);
}

// Round 14
// 264.355 us; speedup vs baseline: 1.0032x; 1.0032x over previous
//
#include <hip/hip_runtime.h>
#include <hip/hip_bf16.h>
#include <math.h>

#define DI __device__ __forceinline__

typedef __attribute__((ext_vector_type(8))) __bf16 bf16x8;
typedef __attribute__((ext_vector_type(8))) short short8;
typedef __attribute__((ext_vector_type(4))) float f32x4;
typedef __attribute__((ext_vector_type(4))) int int4v;
typedef __attribute__((ext_vector_type(4))) unsigned short ushort4v;

// native RTNE f32->bf16 (v_cvt_pk_bf16_f32 on gfx950)
DI short f2bfn(float f) {
  __bf16 b = (__bf16)f;
  short s;
  __builtin_memcpy(&s, &b, 2);
  return s;
}

DI void gload_lds16(const void* g, void* l) {
  __builtin_amdgcn_global_load_lds(
      (const __attribute__((address_space(1))) void*)g,
      (__attribute__((address_space(3))) void*)l, 16, 0, 0);
}

// ---------------- weight transpose + fp32->bf16 convert ----------------
__global__ __launch_bounds__(256) void transpose_cvt(
    const float* __restrict__ in, short* __restrict__ out, int K, int N)
{
  __shared__ float tile[32][33];
  const int tx = threadIdx.x & 31, ty = threadIdx.x >> 5;
  const int n0 = blockIdx.x * 32, k0 = blockIdx.y * 32;
#pragma unroll
  for (int p = 0; p < 4; ++p)
    tile[ty + p * 8][tx] = in[(size_t)(k0 + ty + p * 8) * N + n0 + tx];
  __syncthreads();
#pragma unroll
  for (int p = 0; p < 4; ++p)
    out[(size_t)(n0 + ty + p * 8) * K + k0 + tx] = f2bfn(tile[tx][ty + p * 8]);
}

// ---------------- V transpose: vT[(b*8+h)*96 + d][n] = V[b][n][h*96+d] ----
__global__ __launch_bounds__(256) void v_transpose(
    const short* __restrict__ qkv, short* __restrict__ vT)
{
  __shared__ short tile[64][98];
  const int t = threadIdx.x;
  const int bh = blockIdx.x, nt = blockIdx.y;
  const int b = bh >> 3, h = bh & 7;
  const size_t gbase = (size_t)(b * 1024 + nt * 64) * 2304 + 1536 + h * 96;
#pragma unroll
  for (int i = 0; i < 3; ++i) {
    const int p = i * 256 + t;
    const int row = p / 12, cb = p % 12;
    const short8 v = *(const short8*)(qkv + gbase + (size_t)row * 2304 + cb * 8);
#pragma unroll
    for (int j = 0; j < 4; ++j) {
      unsigned pk = (unsigned)(unsigned short)v[2 * j] |
                    ((unsigned)(unsigned short)v[2 * j + 1] << 16);
      *(unsigned*)&tile[row][cb * 8 + 2 * j] = pk;
    }
  }
  __syncthreads();
#pragma unroll
  for (int i = 0; i < 3; ++i) {
    const int p = i * 256 + t;
    const int d = p >> 3, cb = p & 7;
    short8 o;
#pragma unroll
    for (int j = 0; j < 8; ++j) o[j] = tile[cb * 8 + j][d];
    *(short8*)(vT + ((size_t)bh * 96 + d) * 1024 + nt * 64 + cb * 8) = o;
  }
}

// ---------------- layernorm: 1 wave per row of 768, fp32 in, bf16 out ----
__global__ __launch_bounds__(256) void ln_rows(
    const float* __restrict__ x, const float* __restrict__ gw,
    const float* __restrict__ bw, unsigned short* __restrict__ out)
{
  const int wv = threadIdx.x >> 6, ln = threadIdx.x & 63;
  const size_t row = (size_t)blockIdx.x * 4 + wv;
  const float* xr = x + row * 768;
  float4 v[3];
  float s = 0.f, sq = 0.f;
#pragma unroll
  for (int i = 0; i < 3; ++i) {
    v[i] = *(const float4*)(xr + i * 256 + ln * 4);
    s  += v[i].x + v[i].y + v[i].z + v[i].w;
    sq += v[i].x * v[i].x + v[i].y * v[i].y + v[i].z * v[i].z + v[i].w * v[i].w;
  }
#pragma unroll
  for (int msk = 1; msk < 64; msk <<= 1) {
    s  += __shfl_xor(s, msk);
    sq += __shfl_xor(sq, msk);
  }
  const float mean = s * (1.f / 768.f);
  const float var  = sq * (1.f / 768.f) - mean * mean;
  const float rstd = rsqrtf(var + 1e-5f);
#pragma unroll
  for (int i = 0; i < 3; ++i) {
    const int c = i * 256 + ln * 4;
    const float vals[4] = {v[i].x, v[i].y, v[i].z, v[i].w};
    ushort4v o;
#pragma unroll
    for (int j = 0; j < 4; ++j)
      o[j] = (unsigned short)f2bfn((vals[j] - mean) * rstd * gw[c + j] + bw[c + j]);
    *(ushort4v*)(out + row * 768 + c) = o;
  }
}

// ---------------- GEMM v5: C[M,N] = A[M,K] * Bt[N,K]^T + epilogue ---------
// Per K-step: [vmcnt(LOADS)+barrierA] -> frag reads + MFMAs (compiler
// interleaves with fine lgkmcnt) -> [lgkmcnt(0)+barrierB] -> stage(kt+2).
// Counted vmcnt (T4): loads retire in order, so vmcnt(LOADS) proves
// stage(kt) landed while stage(kt+1)/(kt+2) stay in flight. Both-sides
// chunk-XOR swizzle (rule #21). LDS-bounce epilogue.
enum { EPI_BF16 = 0, EPI_F32_RES = 1, EPI_BF16_GELU = 2, EPI_F32 = 3 };
#define EPITCH 132

template <int MODE, int BM, int BK, int MW>
__global__ __launch_bounds__(256, MW) void gemm_bt(
    const short* __restrict__ A,    // pitch = K
    const short* __restrict__ Bt,   // pitch = K
    const float* __restrict__ bias,
    const float* __restrict__ resid,  // pitch = ldc (fp32) when used
    void* __restrict__ Cout, int ldc,
    int Ntiles, int K)
{
  constexpr int NCHUNK = BK / 8;
  constexpr int CMASK = NCHUNK - 1;
  constexpr int ABYTES = BM * BK * 2;
  constexpr int STAGE_BYTES = (BM + 128) * BK * 2;
  constexpr int NLA = BM * BK / 8 / 256;
  constexpr int NLB = 128 * BK / 8 / 256;
  constexpr int LOADS = NLA + NLB;
  constexpr int MR = BM / 32;
  constexpr int NKK = BK / 32;
  constexpr int SMEM = 2 * STAGE_BYTES > 32 * EPITCH * 4 ? 2 * STAGE_BYTES
                                                         : 32 * EPITCH * 4;
  __shared__ __align__(16) char smem[SMEM];
  const int t = threadIdx.x;
  const int wv = t >> 6, ln = t & 63;
  const int g = ln >> 4, r = ln & 15;
  const int sw = ((int)blockIdx.x & 7) * ((int)gridDim.x >> 3) + ((int)blockIdx.x >> 3);
  const int bm = sw / Ntiles, bn = sw % Ntiles;
  const int wr = wv >> 1, wc = wv & 1;
  f32x4 acc[MR][4] = {};

  // staging source pointers (pre-swizzled), advanced by BK elems per stage
  const char* aptr[NLA];
  const char* bptr[NLB];
#pragma unroll
  for (int q = 0; q < NLA; ++q) {
    const int p = q * 256 + t;
    const int row = p / NCHUNK, c = (p & CMASK) ^ (row & CMASK);
    aptr[q] = (const char*)(A + (size_t)(bm * BM + row) * K + c * 8);
  }
#pragma unroll
  for (int q = 0; q < NLB; ++q) {
    const int p = q * 256 + t;
    const int row = p / NCHUNK, c = (p & CMASK) ^ (row & CMASK);
    bptr[q] = (const char*)(Bt + (size_t)(bn * 128 + row) * K + c * 8);
  }

  auto stage = [&](int buf) {
    char* as = smem + buf * STAGE_BYTES;
    char* bs = as + ABYTES;
#pragma unroll
    for (int q = 0; q < NLA; ++q) {
      gload_lds16(aptr[q], as + q * 4096 + wv * 1024);
      aptr[q] += BK * 2;
    }
#pragma unroll
    for (int q = 0; q < NLB; ++q) {
      gload_lds16(bptr[q], bs + q * 4096 + wv * 1024);
      bptr[q] += BK * 2;
    }
  };

  const int nk = K / BK;
  stage(0);
  stage(1);
  int cur = 0;
  for (int kt = 0; kt < nk; ++kt) {
    // barrier A: my stage(kt) landed (in-order retire) + all waves ditto
    if (kt + 1 < nk)
      asm volatile("s_waitcnt vmcnt(%0)\n\ts_barrier" :: "n"(LOADS) : "memory");
    else
      asm volatile("s_waitcnt vmcnt(0)\n\ts_barrier" ::: "memory");
    const short* as = (const short*)(smem + cur * STAGE_BYTES);
    const short* bs = as + ABYTES / 2;
    bf16x8 af[MR][NKK], bfr[4][NKK];
#pragma unroll
    for (int m = 0; m < MR; ++m) {
      const int row = wr * (BM / 2) + m * 16 + r;
#pragma unroll
      for (int kk = 0; kk < NKK; ++kk)
        af[m][kk] = *(const bf16x8*)(as + row * BK + (((kk * 4 + g) ^ (row & CMASK)) << 3));
    }
#pragma unroll
    for (int n = 0; n < 4; ++n) {
      const int row = wc * 64 + n * 16 + r;
#pragma unroll
      for (int kk = 0; kk < NKK; ++kk)
        bfr[n][kk] = *(const bf16x8*)(bs + row * BK + (((kk * 4 + g) ^ (row & CMASK)) << 3));
    }
    // MFMAs: compiler interleaves with the ds_reads via partial lgkmcnt
#pragma unroll
    for (int kk = 0; kk < NKK; ++kk)
#pragma unroll
      for (int m = 0; m < MR; ++m)
#pragma unroll
        for (int n = 0; n < 4; ++n)
          acc[m][n] = __builtin_amdgcn_mfma_f32_16x16x32_bf16(af[m][kk], bfr[n][kk],
                                                              acc[m][n], 0, 0, 0);
    if (kt + 2 < nk) {
      // barrier B: my reads complete + all waves done reading buf[cur]
      asm volatile("s_waitcnt lgkmcnt(0)\n\ts_barrier" ::: "memory");
      stage(cur);  // overwrite freed buffer (lands by body kt+2's barrier A)
    }
    cur ^= 1;
  }
  __syncthreads();  // full drain before epilogue reuses smem

  // ---- epilogue: LDS bounce, coalesced stores ----
  float* epi = (float*)smem;
  const int cq = (t & 7) * 16;
  const int c0 = bn * 128 + cq;
  f32x4 bv[4];
#pragma unroll
  for (int j = 0; j < 4; ++j) bv[j] = *(const f32x4*)(bias + c0 + j * 4);

#pragma unroll
  for (int m = 0; m < MR; ++m) {
#pragma unroll
    for (int n = 0; n < 4; ++n) {
      const int col = wc * 64 + n * 16 + r;
#pragma unroll
      for (int q = 0; q < 4; ++q)
        epi[(wr * 16 + g * 4 + q) * EPITCH + col] = acc[m][n][q];
    }
    __syncthreads();
    const int lr = t >> 3;
    const size_t grow = (size_t)(bm * BM + (lr < 16 ? m * 16 + lr
                                                    : BM / 2 + m * 16 + (lr - 16)));
    float vals[16];
#pragma unroll
    for (int j = 0; j < 4; ++j) {
      const f32x4 vv = *(const f32x4*)(epi + lr * EPITCH + cq + j * 4);
#pragma unroll
      for (int e = 0; e < 4; ++e) vals[j * 4 + e] = vv[e] + bv[j][e];
    }
    if constexpr (MODE == EPI_F32_RES) {
#pragma unroll
      for (int j = 0; j < 4; ++j) {
        const f32x4 rv = *(const f32x4*)(resid + grow * ldc + c0 + j * 4);
#pragma unroll
        for (int e = 0; e < 4; ++e) vals[j * 4 + e] += rv[e];
      }
    }
    if constexpr (MODE == EPI_BF16_GELU) {
#pragma unroll
      for (int j = 0; j < 16; ++j)
        vals[j] = 0.5f * vals[j] * (1.0f + erff(vals[j] * 0.70710678118654752f));
    }
    if constexpr (MODE == EPI_F32 || MODE == EPI_F32_RES) {
      float* op = (float*)Cout + grow * ldc + c0;
#pragma unroll
      for (int j = 0; j < 4; ++j) {
        f32x4 ov;
#pragma unroll
        for (int e = 0; e < 4; ++e) ov[e] = vals[j * 4 + e];
        *(f32x4*)(op + j * 4) = ov;
      }
    } else {
      unsigned short* op = (unsigned short*)Cout + grow * ldc + c0;
#pragma unroll
      for (int hhalf = 0; hhalf < 2; ++hhalf) {
        short8 ov;
#pragma unroll
        for (int e = 0; e < 8; ++e) ov[e] = f2bfn(vals[hhalf * 8 + e]);
        *(short8*)(op + hhalf * 8) = ov;
      }
    }
    __syncthreads();
  }
}

// ---------------- flash attention v6: swapped QK^T (lane-major softmax) --
// (unchanged from round 10)
__global__ __launch_bounds__(256, 2) void attn_fwd(
    const short* __restrict__ qkv, const short* __restrict__ vT,
    unsigned short* __restrict__ ab)
{
  __shared__ short Ks[2][64 * 128];    // 32 KB
  __shared__ short Vs[2][96 * 64];     // 24 KB
  __shared__ short Ps[4][2][16 * 64];  // 16 KB
  const int t = threadIdx.x, wv = t >> 6, ln = t & 63;
  const int g = ln >> 4, r = ln & 15;
  const int bid = ((int)blockIdx.x & 7) * 64 + ((int)blockIdx.x >> 3);
  const int bh = bid >> 3, qt = bid & 7;
  const int b = bh >> 3, h = bh & 7;

  bf16x8 qf[2][3];
#pragma unroll
  for (int u = 0; u < 2; ++u) {
    const size_t rowq = (size_t)(b * 1024 + qt * 128 + wv * 32 + u * 16 + r);
#pragma unroll
    for (int kd = 0; kd < 3; ++kd)
      qf[u][kd] = *(const bf16x8*)(qkv + rowq * 2304 + h * 96 + kd * 32 + g * 8);
  }

  size_t offK[4];
#pragma unroll
  for (int i = 0; i < 4; ++i) {
    const int p = i * 256 + t;
    const int row = p >> 4, cb = p & 15, cbs = cb ^ (row & 7);
    offK[i] = (size_t)row * 2304 + 768 + h * 96 + (cbs << 3);
  }
  size_t offV[3];
#pragma unroll
  for (int i = 0; i < 3; ++i) {
    const int p = i * 256 + t;
    const int row = p >> 3, cb = p & 7, cbs = cb ^ (row & 7);
    offV[i] = ((size_t)bh * 96 + row) * 1024 + (cbs << 3);
  }
  const short* qb = qkv + (size_t)b * 1024 * 2304;

  auto stageKV = [&](int buf, int kt) {
    const size_t kadd = (size_t)kt * 64 * 2304;
#pragma unroll
    for (int i = 0; i < 4; ++i)
      gload_lds16(qb + kadd + offK[i], (char*)Ks[buf] + i * 4096 + wv * 1024);
#pragma unroll
    for (int i = 0; i < 3; ++i)
      gload_lds16(vT + offV[i] + kt * 64, (char*)Vs[buf] + i * 4096 + wv * 1024);
  };

  f32x4 o[2][6] = {};
  float mr[2] = {-1e30f, -1e30f}, lr[2] = {0.f, 0.f};  // stats for q-row r

  stageKV(0, 0);
  __syncthreads();
  int cur = 0;
  for (int kt = 0; kt < 16; ++kt) {
    if (kt < 15) stageKV(cur ^ 1, kt + 1);
    const short* ks = Ks[cur];
    const short* vs = Vs[cur];

    // ---- S^T = K Q^T for BOTH u, sharing each kf fragment ----
    f32x4 s[2][4] = {};
    __builtin_amdgcn_s_setprio(1);
#pragma unroll
    for (int sub = 0; sub < 4; ++sub) {
      bf16x8 kf[3];
#pragma unroll
      for (int kd = 0; kd < 3; ++kd)
        kf[kd] = *(const bf16x8*)(
            ks + (sub * 16 + r) * 128 + (((kd * 4 + g) ^ (r & 7)) << 3));
#pragma unroll
      for (int u = 0; u < 2; ++u)
#pragma unroll
        for (int kd = 0; kd < 3; ++kd)
          s[u][sub] = __builtin_amdgcn_mfma_f32_16x16x32_bf16(kf[kd], qf[u][kd],
                                                              s[u][sub], 0, 0, 0);
    }
    __builtin_amdgcn_s_setprio(0);

    // ---- lane-major online softmax per u ----
#pragma unroll
    for (int u = 0; u < 2; ++u) {
      float tm = fmaxf(fmaxf(s[u][0][0], s[u][0][1]),
                       fmaxf(s[u][0][2], s[u][0][3]));
#pragma unroll
      for (int sub = 1; sub < 4; ++sub)
        tm = fmaxf(tm, fmaxf(fmaxf(s[u][sub][0], s[u][sub][1]),
                             fmaxf(s[u][sub][2], s[u][sub][3])));
      tm = fmaxf(tm, __shfl_xor(tm, 16));
      tm = fmaxf(tm, __shfl_xor(tm, 32));

      if (__any(tm > mr[u] + 8.f)) {   // defer-max: rescale rarely
        const float mnew = fmaxf(mr[u], tm);
        const float sc = __expf(mr[u] - mnew);
        lr[u] *= sc;
        mr[u] = mnew;
        float scr[4];
#pragma unroll
        for (int reg = 0; reg < 4; ++reg)
          scr[reg] = __shfl(sc, (ln & 48) | (g * 4 + reg));
#pragma unroll
        for (int nd = 0; nd < 6; ++nd)
#pragma unroll
          for (int reg = 0; reg < 4; ++reg) o[u][nd][reg] *= scr[reg];
      }

      float tsum = 0.f;
#pragma unroll
      for (int sub = 0; sub < 4; ++sub) {
        float p0 = __expf(s[u][sub][0] - mr[u]);
        float p1 = __expf(s[u][sub][1] - mr[u]);
        float p2 = __expf(s[u][sub][2] - mr[u]);
        float p3 = __expf(s[u][sub][3] - mr[u]);
        tsum += (p0 + p1) + (p2 + p3);
        ushort4v pk;
        pk[0] = (unsigned short)f2bfn(p0);
        pk[1] = (unsigned short)f2bfn(p1);
        pk[2] = (unsigned short)f2bfn(p2);
        pk[3] = (unsigned short)f2bfn(p3);
        const int c8 = (sub * 4 + g) ^ ((r & 7) << 1);
        *(ushort4v*)((char*)Ps[wv][u] + r * 128 + c8 * 8) = pk;
      }
      tsum += __shfl_xor(tsum, 16);
      tsum += __shfl_xor(tsum, 32);
      lr[u] += tsum;
    }

    // ---- O += P V for BOTH u, sharing each vf fragment ----
    bf16x8 pf[2][2];
#pragma unroll
    for (int u = 0; u < 2; ++u)
#pragma unroll
      for (int kk = 0; kk < 2; ++kk)
        pf[u][kk] = *(const bf16x8*)(
            Ps[wv][u] + r * 64 + (((kk * 4 + g) ^ (r & 7)) << 3));
    __builtin_amdgcn_s_setprio(1);
#pragma unroll
    for (int nd = 0; nd < 6; ++nd) {
      bf16x8 vf[2];
#pragma unroll
      for (int kk = 0; kk < 2; ++kk)
        vf[kk] = *(const bf16x8*)(
            vs + (nd * 16 + r) * 64 + (((kk * 4 + g) ^ (r & 7)) << 3));
#pragma unroll
      for (int u = 0; u < 2; ++u)
#pragma unroll
        for (int kk = 0; kk < 2; ++kk)
          o[u][nd] = __builtin_amdgcn_mfma_f32_16x16x32_bf16(pf[u][kk], vf[kk],
                                                             o[u][nd], 0, 0, 0);
    }
    __builtin_amdgcn_s_setprio(0);

    __syncthreads();  // drains stage(kt+1); frees cur for rewrite
    cur ^= 1;
  }

  // epilogue: O * (96 / l); l for o-row g*4+reg fetched from lane r'=row
#pragma unroll
  for (int u = 0; u < 2; ++u) {
    float linv[4];
#pragma unroll
    for (int reg = 0; reg < 4; ++reg)
      linv[reg] = 96.0f / __shfl(lr[u], (ln & 48) | (g * 4 + reg));
#pragma unroll
    for (int reg = 0; reg < 4; ++reg) {
      const size_t row = (size_t)(b * 1024 + qt * 128 + wv * 32 + u * 16 + g * 4 + reg);
#pragma unroll
      for (int nd = 0; nd < 6; ++nd)
        ab[row * 768 + h * 96 + nd * 16 + r] =
            (unsigned short)f2bfn(o[u][nd][reg] * linv[reg]);
    }
  }
}

// ------------------------------------------------------------------------
extern "C" void kernel_launch(void* const* d_in, const int* in_sizes, int n_in,
                              void* d_out, int out_size, void* d_ws, size_t ws_size,
                              hipStream_t stream)
{
  const float* x    = (const float*)d_in[0];
  const float* ln1g = (const float*)d_in[1];
  const float* ln1b = (const float*)d_in[2];
  const float* Wq   = (const float*)d_in[3];
  const float* bq   = (const float*)d_in[4];
  const float* Wk   = (const float*)d_in[5];
  const float* bk   = (const float*)d_in[6];
  const float* Wv   = (const float*)d_in[7];
  const float* bv   = (const float*)d_in[8];
  const float* Wo   = (const float*)d_in[9];
  const float* bo   = (const float*)d_in[10];
  const float* ln2g = (const float*)d_in[11];
  const float* ln2b = (const float*)d_in[12];
  const float* W1   = (const float*)d_in[13];
  const float* b1   = (const float*)d_in[14];
  const float* W2   = (const float*)d_in[15];
  const float* b2   = (const float*)d_in[16];

  char* ws = (char*)d_ws;
  size_t off = 0;
  short* Wtqkv = (short*)(ws + off); off += (size_t)2304 * 768 * 2;
  short* Wto   = (short*)(ws + off); off += (size_t)768 * 768 * 2;
  short* Wt1   = (short*)(ws + off); off += (size_t)3072 * 768 * 2;
  short* Wt2   = (short*)(ws + off); off += (size_t)768 * 3072 * 2;
  float* bqkv  = (float*)(ws + off); off += 16384;
  short* hb    = (short*)(ws + off); off += (size_t)8192 * 768 * 2;
  short* qkv   = (short*)(ws + off); off += (size_t)8192 * 2304 * 2;
  short* h2b   = (short*)(ws + off); off += (size_t)8192 * 768 * 2;
  short* f1 = hb;          // [8192][3072] bf16, overlays hb+qkv (both dead)
  short* ab = hb;          // attention output overlays hb
  short* vT = h2b;         // V^T [64*96][1024], overlays h2b
  float* x1 = (float*)d_out;  // residual stream parked in d_out

  transpose_cvt<<<dim3(24, 24), 256, 0, stream>>>(Wq, Wtqkv, 768, 768);
  transpose_cvt<<<dim3(24, 24), 256, 0, stream>>>(Wk, Wtqkv + (size_t)768 * 768, 768, 768);
  transpose_cvt<<<dim3(24, 24), 256, 0, stream>>>(Wv, Wtqkv + (size_t)1536 * 768, 768, 768);
  transpose_cvt<<<dim3(24, 24), 256, 0, stream>>>(Wo, Wto, 768, 768);
  transpose_cvt<<<dim3(96, 24), 256, 0, stream>>>(W1, Wt1, 768, 3072);
  transpose_cvt<<<dim3(24, 96), 256, 0, stream>>>(W2, Wt2, 3072, 768);
  hipMemcpyAsync(bqkv,        bq, 768 * sizeof(float), hipMemcpyDeviceToDevice, stream);
  hipMemcpyAsync(bqkv + 768,  bk, 768 * sizeof(float), hipMemcpyDeviceToDevice, stream);
  hipMemcpyAsync(bqkv + 1536, bv, 768 * sizeof(float), hipMemcpyDeviceToDevice, stream);

  ln_rows<<<2048, 256, 0, stream>>>(x, ln1g, ln1b, (unsigned short*)hb);
  gemm_bt<EPI_BF16, 128, 32, 4><<<64 * 18, 256, 0, stream>>>(hb, Wtqkv, bqkv, nullptr, qkv, 2304, 18, 768);
  v_transpose<<<dim3(64, 16), 256, 0, stream>>>(qkv, vT);
  attn_fwd<<<512, 256, 0, stream>>>(qkv, vT, (unsigned short*)ab);
  gemm_bt<EPI_F32_RES, 64, 64, 3><<<128 * 6, 256, 0, stream>>>(ab, Wto, bo, x, x1, 768, 6, 768);

  ln_rows<<<2048, 256, 0, stream>>>(x1, ln2g, ln2b, (unsigned short*)h2b);
  gemm_bt<EPI_BF16_GELU, 128, 32, 4><<<64 * 24, 256, 0, stream>>>(h2b, Wt1, b1, nullptr, f1, 3072, 24, 768);
  gemm_bt<EPI_F32, 64, 64, 3><<<128 * 6, 256, 0, stream>>>(f1, Wt2, b2, nullptr, (float*)d_out, 768, 6, 3072);
}

// Round 15
// 262.946 us; speedup vs baseline: 1.0086x; 1.0054x over previous
//
#include <hip/hip_runtime.h>
#include <hip/hip_bf16.h>
#include <math.h>

#define DI __device__ __forceinline__

typedef __attribute__((ext_vector_type(8))) __bf16 bf16x8;
typedef __attribute__((ext_vector_type(8))) short short8;
typedef __attribute__((ext_vector_type(4))) float f32x4;
typedef __attribute__((ext_vector_type(4))) int int4v;
typedef __attribute__((ext_vector_type(4))) unsigned short ushort4v;

// native RTNE f32->bf16 (v_cvt_pk_bf16_f32 on gfx950)
DI short f2bfn(float f) {
  __bf16 b = (__bf16)f;
  short s;
  __builtin_memcpy(&s, &b, 2);
  return s;
}

// Abramowitz-Stegun 7.1.26 erf (max abs err 1.5e-7): ~12 VALU ops vs the
// erff libcall's ~30. exp via v_exp_f32 (__expf).
DI float erf_fast(float x) {
  const float ax = fabsf(x);
  const float t = __builtin_amdgcn_rcpf(1.0f + 0.3275911f * ax);
  float p = 1.061405429f;
  p = p * t - 1.453152027f;
  p = p * t + 1.421413741f;
  p = p * t - 0.284496736f;
  p = p * t + 0.254829592f;
  p = p * t;
  const float r = 1.0f - p * __expf(-ax * ax);
  return copysignf(r, x);
}

DI void gload_lds16(const void* g, void* l) {
  __builtin_amdgcn_global_load_lds(
      (const __attribute__((address_space(1))) void*)g,
      (__attribute__((address_space(3))) void*)l, 16, 0, 0);
}

// ---------------- weight transpose + fp32->bf16 convert ----------------
__global__ __launch_bounds__(256) void transpose_cvt(
    const float* __restrict__ in, short* __restrict__ out, int K, int N)
{
  __shared__ float tile[32][33];
  const int tx = threadIdx.x & 31, ty = threadIdx.x >> 5;
  const int n0 = blockIdx.x * 32, k0 = blockIdx.y * 32;
#pragma unroll
  for (int p = 0; p < 4; ++p)
    tile[ty + p * 8][tx] = in[(size_t)(k0 + ty + p * 8) * N + n0 + tx];
  __syncthreads();
#pragma unroll
  for (int p = 0; p < 4; ++p)
    out[(size_t)(n0 + ty + p * 8) * K + k0 + tx] = f2bfn(tile[tx][ty + p * 8]);
}

// ---------------- V transpose: vT[(b*8+h)*96 + d][n] = V[b][n][h*96+d] ----
__global__ __launch_bounds__(256) void v_transpose(
    const short* __restrict__ qkv, short* __restrict__ vT)
{
  __shared__ short tile[64][98];
  const int t = threadIdx.x;
  const int bh = blockIdx.x, nt = blockIdx.y;
  const int b = bh >> 3, h = bh & 7;
  const size_t gbase = (size_t)(b * 1024 + nt * 64) * 2304 + 1536 + h * 96;
#pragma unroll
  for (int i = 0; i < 3; ++i) {
    const int p = i * 256 + t;
    const int row = p / 12, cb = p % 12;
    const short8 v = *(const short8*)(qkv + gbase + (size_t)row * 2304 + cb * 8);
#pragma unroll
    for (int j = 0; j < 4; ++j) {
      unsigned pk = (unsigned)(unsigned short)v[2 * j] |
                    ((unsigned)(unsigned short)v[2 * j + 1] << 16);
      *(unsigned*)&tile[row][cb * 8 + 2 * j] = pk;
    }
  }
  __syncthreads();
#pragma unroll
  for (int i = 0; i < 3; ++i) {
    const int p = i * 256 + t;
    const int d = p >> 3, cb = p & 7;
    short8 o;
#pragma unroll
    for (int j = 0; j < 8; ++j) o[j] = tile[cb * 8 + j][d];
    *(short8*)(vT + ((size_t)bh * 96 + d) * 1024 + nt * 64 + cb * 8) = o;
  }
}

// ---------------- layernorm: 1 wave per row of 768, fp32 in, bf16 out ----
__global__ __launch_bounds__(256) void ln_rows(
    const float* __restrict__ x, const float* __restrict__ gw,
    const float* __restrict__ bw, unsigned short* __restrict__ out)
{
  const int wv = threadIdx.x >> 6, ln = threadIdx.x & 63;
  const size_t row = (size_t)blockIdx.x * 4 + wv;
  const float* xr = x + row * 768;
  float4 v[3];
  float s = 0.f, sq = 0.f;
#pragma unroll
  for (int i = 0; i < 3; ++i) {
    v[i] = *(const float4*)(xr + i * 256 + ln * 4);
    s  += v[i].x + v[i].y + v[i].z + v[i].w;
    sq += v[i].x * v[i].x + v[i].y * v[i].y + v[i].z * v[i].z + v[i].w * v[i].w;
  }
#pragma unroll
  for (int msk = 1; msk < 64; msk <<= 1) {
    s  += __shfl_xor(s, msk);
    sq += __shfl_xor(sq, msk);
  }
  const float mean = s * (1.f / 768.f);
  const float var  = sq * (1.f / 768.f) - mean * mean;
  const float rstd = rsqrtf(var + 1e-5f);
#pragma unroll
  for (int i = 0; i < 3; ++i) {
    const int c = i * 256 + ln * 4;
    const float vals[4] = {v[i].x, v[i].y, v[i].z, v[i].w};
    ushort4v o;
#pragma unroll
    for (int j = 0; j < 4; ++j)
      o[j] = (unsigned short)f2bfn((vals[j] - mean) * rstd * gw[c + j] + bw[c + j]);
    *(ushort4v*)(out + row * 768 + c) = o;
  }
}

// ---------------- GEMM v6: C[M,N] = A[M,K] * Bt[N,K]^T + epilogue ---------
// K-loop unchanged (2-deep counted-vmcnt, both-sides chunk-XOR swizzle).
// Epilogue: WAVE-PRIVATE 16x68 fp32 LDS bounce — zero barriers (wave-
// internal DS ordering); fast-erf GELU.
enum { EPI_BF16 = 0, EPI_F32_RES = 1, EPI_BF16_GELU = 2, EPI_F32 = 3 };

template <int MODE, int BM, int BK, int MW>
__global__ __launch_bounds__(256, MW) void gemm_bt(
    const short* __restrict__ A,    // pitch = K
    const short* __restrict__ Bt,   // pitch = K
    const float* __restrict__ bias,
    const float* __restrict__ resid,  // pitch = ldc (fp32) when used
    void* __restrict__ Cout, int ldc,
    int Ntiles, int K)
{
  constexpr int NCHUNK = BK / 8;
  constexpr int CMASK = NCHUNK - 1;
  constexpr int ABYTES = BM * BK * 2;
  constexpr int STAGE_BYTES = (BM + 128) * BK * 2;
  constexpr int NLA = BM * BK / 8 / 256;
  constexpr int NLB = 128 * BK / 8 / 256;
  constexpr int LOADS = NLA + NLB;
  constexpr int MR = BM / 32;
  constexpr int NKK = BK / 32;
  constexpr int SMEM = 2 * STAGE_BYTES > 4 * 4352 ? 2 * STAGE_BYTES : 4 * 4352;
  __shared__ __align__(16) char smem[SMEM];
  const int t = threadIdx.x;
  const int wv = t >> 6, ln = t & 63;
  const int g = ln >> 4, r = ln & 15;
  const int sw = ((int)blockIdx.x & 7) * ((int)gridDim.x >> 3) + ((int)blockIdx.x >> 3);
  const int bm = sw / Ntiles, bn = sw % Ntiles;
  const int wr = wv >> 1, wc = wv & 1;
  f32x4 acc[MR][4] = {};

  // staging source pointers (pre-swizzled), advanced by BK elems per stage
  const char* aptr[NLA];
  const char* bptr[NLB];
#pragma unroll
  for (int q = 0; q < NLA; ++q) {
    const int p = q * 256 + t;
    const int row = p / NCHUNK, c = (p & CMASK) ^ (row & CMASK);
    aptr[q] = (const char*)(A + (size_t)(bm * BM + row) * K + c * 8);
  }
#pragma unroll
  for (int q = 0; q < NLB; ++q) {
    const int p = q * 256 + t;
    const int row = p / NCHUNK, c = (p & CMASK) ^ (row & CMASK);
    bptr[q] = (const char*)(Bt + (size_t)(bn * 128 + row) * K + c * 8);
  }

  auto stage = [&](int buf) {
    char* as = smem + buf * STAGE_BYTES;
    char* bs = as + ABYTES;
#pragma unroll
    for (int q = 0; q < NLA; ++q) {
      gload_lds16(aptr[q], as + q * 4096 + wv * 1024);
      aptr[q] += BK * 2;
    }
#pragma unroll
    for (int q = 0; q < NLB; ++q) {
      gload_lds16(bptr[q], bs + q * 4096 + wv * 1024);
      bptr[q] += BK * 2;
    }
  };

  const int nk = K / BK;
  stage(0);
  stage(1);
  int cur = 0;
  for (int kt = 0; kt < nk; ++kt) {
    // barrier A: my stage(kt) landed (in-order retire) + all waves ditto
    if (kt + 1 < nk)
      asm volatile("s_waitcnt vmcnt(%0)\n\ts_barrier" :: "n"(LOADS) : "memory");
    else
      asm volatile("s_waitcnt vmcnt(0)\n\ts_barrier" ::: "memory");
    const short* as = (const short*)(smem + cur * STAGE_BYTES);
    const short* bs = as + ABYTES / 2;
    bf16x8 af[MR][NKK], bfr[4][NKK];
#pragma unroll
    for (int m = 0; m < MR; ++m) {
      const int row = wr * (BM / 2) + m * 16 + r;
#pragma unroll
      for (int kk = 0; kk < NKK; ++kk)
        af[m][kk] = *(const bf16x8*)(as + row * BK + (((kk * 4 + g) ^ (row & CMASK)) << 3));
    }
#pragma unroll
    for (int n = 0; n < 4; ++n) {
      const int row = wc * 64 + n * 16 + r;
#pragma unroll
      for (int kk = 0; kk < NKK; ++kk)
        bfr[n][kk] = *(const bf16x8*)(bs + row * BK + (((kk * 4 + g) ^ (row & CMASK)) << 3));
    }
    // MFMAs: compiler interleaves with the ds_reads via partial lgkmcnt
#pragma unroll
    for (int kk = 0; kk < NKK; ++kk)
#pragma unroll
      for (int m = 0; m < MR; ++m)
#pragma unroll
        for (int n = 0; n < 4; ++n)
          acc[m][n] = __builtin_amdgcn_mfma_f32_16x16x32_bf16(af[m][kk], bfr[n][kk],
                                                              acc[m][n], 0, 0, 0);
    if (kt + 2 < nk) {
      // barrier B: my reads complete + all waves done reading buf[cur]
      asm volatile("s_waitcnt lgkmcnt(0)\n\ts_barrier" ::: "memory");
      stage(cur);  // overwrite freed buffer (lands by body kt+2's barrier A)
    }
    cur ^= 1;
  }
  __syncthreads();  // all waves done with stage buffers before epi overwrite

  // ---- epilogue: WAVE-PRIVATE LDS bounce, zero barriers ----
  float* epi = (float*)(smem + wv * 4352);   // 16 x 68 fp32 per wave
  const int cq = (ln & 3) * 16;               // 16-col slice in 64-col strip
  const int lr = ln >> 2;                     // 0..15 row within slab
  const int c0 = bn * 128 + wc * 64 + cq;
  f32x4 bv[4];
#pragma unroll
  for (int j = 0; j < 4; ++j) bv[j] = *(const f32x4*)(bias + c0 + j * 4);

#pragma unroll
  for (int m = 0; m < MR; ++m) {
#pragma unroll
    for (int n = 0; n < 4; ++n)
#pragma unroll
      for (int q = 0; q < 4; ++q)
        epi[(g * 4 + q) * 68 + n * 16 + r] = acc[m][n][q];
    // wave-internal DS ordering: reads below see this wave's writes above
    const size_t grow = (size_t)(bm * BM + wr * (BM / 2) + m * 16 + lr);
    float vals[16];
#pragma unroll
    for (int j = 0; j < 4; ++j) {
      const f32x4 vv = *(const f32x4*)(epi + lr * 68 + cq + j * 4);
#pragma unroll
      for (int e = 0; e < 4; ++e) vals[j * 4 + e] = vv[e] + bv[j][e];
    }
    if constexpr (MODE == EPI_F32_RES) {
#pragma unroll
      for (int j = 0; j < 4; ++j) {
        const f32x4 rv = *(const f32x4*)(resid + grow * ldc + c0 + j * 4);
#pragma unroll
        for (int e = 0; e < 4; ++e) vals[j * 4 + e] += rv[e];
      }
    }
    if constexpr (MODE == EPI_BF16_GELU) {
#pragma unroll
      for (int j = 0; j < 16; ++j)
        vals[j] = 0.5f * vals[j] * (1.0f + erf_fast(vals[j] * 0.70710678118654752f));
    }
    if constexpr (MODE == EPI_F32 || MODE == EPI_F32_RES) {
      float* op = (float*)Cout + grow * ldc + c0;
#pragma unroll
      for (int j = 0; j < 4; ++j) {
        f32x4 ov;
#pragma unroll
        for (int e = 0; e < 4; ++e) ov[e] = vals[j * 4 + e];
        *(f32x4*)(op + j * 4) = ov;
      }
    } else {
      unsigned short* op = (unsigned short*)Cout + grow * ldc + c0;
#pragma unroll
      for (int hhalf = 0; hhalf < 2; ++hhalf) {
        short8 ov;
#pragma unroll
        for (int e = 0; e < 8; ++e) ov[e] = f2bfn(vals[hhalf * 8 + e]);
        *(short8*)(op + hhalf * 8) = ov;
      }
    }
  }
}

// ---------------- flash attention v6: swapped QK^T (lane-major softmax) --
// (unchanged)
__global__ __launch_bounds__(256, 2) void attn_fwd(
    const short* __restrict__ qkv, const short* __restrict__ vT,
    unsigned short* __restrict__ ab)
{
  __shared__ short Ks[2][64 * 128];    // 32 KB
  __shared__ short Vs[2][96 * 64];     // 24 KB
  __shared__ short Ps[4][2][16 * 64];  // 16 KB
  const int t = threadIdx.x, wv = t >> 6, ln = t & 63;
  const int g = ln >> 4, r = ln & 15;
  const int bid = ((int)blockIdx.x & 7) * 64 + ((int)blockIdx.x >> 3);
  const int bh = bid >> 3, qt = bid & 7;
  const int b = bh >> 3, h = bh & 7;

  bf16x8 qf[2][3];
#pragma unroll
  for (int u = 0; u < 2; ++u) {
    const size_t rowq = (size_t)(b * 1024 + qt * 128 + wv * 32 + u * 16 + r);
#pragma unroll
    for (int kd = 0; kd < 3; ++kd)
      qf[u][kd] = *(const bf16x8*)(qkv + rowq * 2304 + h * 96 + kd * 32 + g * 8);
  }

  size_t offK[4];
#pragma unroll
  for (int i = 0; i < 4; ++i) {
    const int p = i * 256 + t;
    const int row = p >> 4, cb = p & 15, cbs = cb ^ (row & 7);
    offK[i] = (size_t)row * 2304 + 768 + h * 96 + (cbs << 3);
  }
  size_t offV[3];
#pragma unroll
  for (int i = 0; i < 3; ++i) {
    const int p = i * 256 + t;
    const int row = p >> 3, cb = p & 7, cbs = cb ^ (row & 7);
    offV[i] = ((size_t)bh * 96 + row) * 1024 + (cbs << 3);
  }
  const short* qb = qkv + (size_t)b * 1024 * 2304;

  auto stageKV = [&](int buf, int kt) {
    const size_t kadd = (size_t)kt * 64 * 2304;
#pragma unroll
    for (int i = 0; i < 4; ++i)
      gload_lds16(qb + kadd + offK[i], (char*)Ks[buf] + i * 4096 + wv * 1024);
#pragma unroll
    for (int i = 0; i < 3; ++i)
      gload_lds16(vT + offV[i] + kt * 64, (char*)Vs[buf] + i * 4096 + wv * 1024);
  };

  f32x4 o[2][6] = {};
  float mr[2] = {-1e30f, -1e30f}, lr[2] = {0.f, 0.f};  // stats for q-row r

  stageKV(0, 0);
  __syncthreads();
  int cur = 0;
  for (int kt = 0; kt < 16; ++kt) {
    if (kt < 15) stageKV(cur ^ 1, kt + 1);
    const short* ks = Ks[cur];
    const short* vs = Vs[cur];

    // ---- S^T = K Q^T for BOTH u, sharing each kf fragment ----
    f32x4 s[2][4] = {};
    __builtin_amdgcn_s_setprio(1);
#pragma unroll
    for (int sub = 0; sub < 4; ++sub) {
      bf16x8 kf[3];
#pragma unroll
      for (int kd = 0; kd < 3; ++kd)
        kf[kd] = *(const bf16x8*)(
            ks + (sub * 16 + r) * 128 + (((kd * 4 + g) ^ (r & 7)) << 3));
#pragma unroll
      for (int u = 0; u < 2; ++u)
#pragma unroll
        for (int kd = 0; kd < 3; ++kd)
          s[u][sub] = __builtin_amdgcn_mfma_f32_16x16x32_bf16(kf[kd], qf[u][kd],
                                                              s[u][sub], 0, 0, 0);
    }
    __builtin_amdgcn_s_setprio(0);

    // ---- lane-major online softmax per u ----
#pragma unroll
    for (int u = 0; u < 2; ++u) {
      float tm = fmaxf(fmaxf(s[u][0][0], s[u][0][1]),
                       fmaxf(s[u][0][2], s[u][0][3]));
#pragma unroll
      for (int sub = 1; sub < 4; ++sub)
        tm = fmaxf(tm, fmaxf(fmaxf(s[u][sub][0], s[u][sub][1]),
                             fmaxf(s[u][sub][2], s[u][sub][3])));
      tm = fmaxf(tm, __shfl_xor(tm, 16));
      tm = fmaxf(tm, __shfl_xor(tm, 32));

      if (__any(tm > mr[u] + 8.f)) {   // defer-max: rescale rarely
        const float mnew = fmaxf(mr[u], tm);
        const float sc = __expf(mr[u] - mnew);
        lr[u] *= sc;
        mr[u] = mnew;
        float scr[4];
#pragma unroll
        for (int reg = 0; reg < 4; ++reg)
          scr[reg] = __shfl(sc, (ln & 48) | (g * 4 + reg));
#pragma unroll
        for (int nd = 0; nd < 6; ++nd)
#pragma unroll
          for (int reg = 0; reg < 4; ++reg) o[u][nd][reg] *= scr[reg];
      }

      float tsum = 0.f;
#pragma unroll
      for (int sub = 0; sub < 4; ++sub) {
        float p0 = __expf(s[u][sub][0] - mr[u]);
        float p1 = __expf(s[u][sub][1] - mr[u]);
        float p2 = __expf(s[u][sub][2] - mr[u]);
        float p3 = __expf(s[u][sub][3] - mr[u]);
        tsum += (p0 + p1) + (p2 + p3);
        ushort4v pk;
        pk[0] = (unsigned short)f2bfn(p0);
        pk[1] = (unsigned short)f2bfn(p1);
        pk[2] = (unsigned short)f2bfn(p2);
        pk[3] = (unsigned short)f2bfn(p3);
        const int c8 = (sub * 4 + g) ^ ((r & 7) << 1);
        *(ushort4v*)((char*)Ps[wv][u] + r * 128 + c8 * 8) = pk;
      }
      tsum += __shfl_xor(tsum, 16);
      tsum += __shfl_xor(tsum, 32);
      lr[u] += tsum;
    }

    // ---- O += P V for BOTH u, sharing each vf fragment ----
    bf16x8 pf[2][2];
#pragma unroll
    for (int u = 0; u < 2; ++u)
#pragma unroll
      for (int kk = 0; kk < 2; ++kk)
        pf[u][kk] = *(const bf16x8*)(
            Ps[wv][u] + r * 64 + (((kk * 4 + g) ^ (r & 7)) << 3));
    __builtin_amdgcn_s_setprio(1);
#pragma unroll
    for (int nd = 0; nd < 6; ++nd) {
      bf16x8 vf[2];
#pragma unroll
      for (int kk = 0; kk < 2; ++kk)
        vf[kk] = *(const bf16x8*)(
            vs + (nd * 16 + r) * 64 + (((kk * 4 + g) ^ (r & 7)) << 3));
#pragma unroll
      for (int u = 0; u < 2; ++u)
#pragma unroll
        for (int kk = 0; kk < 2; ++kk)
          o[u][nd] = __builtin_amdgcn_mfma_f32_16x16x32_bf16(pf[u][kk], vf[kk],
                                                             o[u][nd], 0, 0, 0);
    }
    __builtin_amdgcn_s_setprio(0);

    __syncthreads();  // drains stage(kt+1); frees cur for rewrite
    cur ^= 1;
  }

  // epilogue: O * (96 / l); l for o-row g*4+reg fetched from lane r'=row
#pragma unroll
  for (int u = 0; u < 2; ++u) {
    float linv[4];
#pragma unroll
    for (int reg = 0; reg < 4; ++reg)
      linv[reg] = 96.0f / __shfl(lr[u], (ln & 48) | (g * 4 + reg));
#pragma unroll
    for (int reg = 0; reg < 4; ++reg) {
      const size_t row = (size_t)(b * 1024 + qt * 128 + wv * 32 + u * 16 + g * 4 + reg);
#pragma unroll
      for (int nd = 0; nd < 6; ++nd)
        ab[row * 768 + h * 96 + nd * 16 + r] =
            (unsigned short)f2bfn(o[u][nd][reg] * linv[reg]);
    }
  }
}

// ------------------------------------------------------------------------
extern "C" void kernel_launch(void* const* d_in, const int* in_sizes, int n_in,
                              void* d_out, int out_size, void* d_ws, size_t ws_size,
                              hipStream_t stream)
{
  const float* x    = (const float*)d_in[0];
  const float* ln1g = (const float*)d_in[1];
  const float* ln1b = (const float*)d_in[2];
  const float* Wq   = (const float*)d_in[3];
  const float* bq   = (const float*)d_in[4];
  const float* Wk   = (const float*)d_in[5];
  const float* bk   = (const float*)d_in[6];
  const float* Wv   = (const float*)d_in[7];
  const float* bv   = (const float*)d_in[8];
  const float* Wo   = (const float*)d_in[9];
  const float* bo   = (const float*)d_in[10];
  const float* ln2g = (const float*)d_in[11];
  const float* ln2b = (const float*)d_in[12];
  const float* W1   = (const float*)d_in[13];
  const float* b1   = (const float*)d_in[14];
  const float* W2   = (const float*)d_in[15];
  const float* b2   = (const float*)d_in[16];

  char* ws = (char*)d_ws;
  size_t off = 0;
  short* Wtqkv = (short*)(ws + off); off += (size_t)2304 * 768 * 2;
  short* Wto   = (short*)(ws + off); off += (size_t)768 * 768 * 2;
  short* Wt1   = (short*)(ws + off); off += (size_t)3072 * 768 * 2;
  short* Wt2   = (short*)(ws + off); off += (size_t)768 * 3072 * 2;
  float* bqkv  = (float*)(ws + off); off += 16384;
  short* hb    = (short*)(ws + off); off += (size_t)8192 * 768 * 2;
  short* qkv   = (short*)(ws + off); off += (size_t)8192 * 2304 * 2;
  short* h2b   = (short*)(ws + off); off += (size_t)8192 * 768 * 2;
  short* f1 = hb;          // [8192][3072] bf16, overlays hb+qkv (both dead)
  short* ab = hb;          // attention output overlays hb
  short* vT = h2b;         // V^T [64*96][1024], overlays h2b
  float* x1 = (float*)d_out;  // residual stream parked in d_out

  transpose_cvt<<<dim3(24, 24), 256, 0, stream>>>(Wq, Wtqkv, 768, 768);
  transpose_cvt<<<dim3(24, 24), 256, 0, stream>>>(Wk, Wtqkv + (size_t)768 * 768, 768, 768);
  transpose_cvt<<<dim3(24, 24), 256, 0, stream>>>(Wv, Wtqkv + (size_t)1536 * 768, 768, 768);
  transpose_cvt<<<dim3(24, 24), 256, 0, stream>>>(Wo, Wto, 768, 768);
  transpose_cvt<<<dim3(96, 24), 256, 0, stream>>>(W1, Wt1, 768, 3072);
  transpose_cvt<<<dim3(24, 96), 256, 0, stream>>>(W2, Wt2, 3072, 768);
  hipMemcpyAsync(bqkv,        bq, 768 * sizeof(float), hipMemcpyDeviceToDevice, stream);
  hipMemcpyAsync(bqkv + 768,  bk, 768 * sizeof(float), hipMemcpyDeviceToDevice, stream);
  hipMemcpyAsync(bqkv + 1536, bv, 768 * sizeof(float), hipMemcpyDeviceToDevice, stream);

  ln_rows<<<2048, 256, 0, stream>>>(x, ln1g, ln1b, (unsigned short*)hb);
  gemm_bt<EPI_BF16, 128, 32, 4><<<64 * 18, 256, 0, stream>>>(hb, Wtqkv, bqkv, nullptr, qkv, 2304, 18, 768);
  v_transpose<<<dim3(64, 16), 256, 0, stream>>>(qkv, vT);
  attn_fwd<<<512, 256, 0, stream>>>(qkv, vT, (unsigned short*)ab);
  gemm_bt<EPI_F32_RES, 64, 64, 3><<<128 * 6, 256, 0, stream>>>(ab, Wto, bo, x, x1, 768, 6, 768);

  ln_rows<<<2048, 256, 0, stream>>>(x1, ln2g, ln2b, (unsigned short*)h2b);
  gemm_bt<EPI_BF16_GELU, 128, 32, 4><<<64 * 24, 256, 0, stream>>>(h2b, Wt1, b1, nullptr, f1, 3072, 24, 768);
  gemm_bt<EPI_F32, 64, 64, 3><<<128 * 6, 256, 0, stream>>>(f1, Wt2, b2, nullptr, (float*)d_out, 768, 6, 3072);
}

// Round 16
// 242.325 us; speedup vs baseline: 1.0944x; 1.0851x over previous
//
#include <hip/hip_runtime.h>
#include <hip/hip_bf16.h>
#include <math.h>

#define DI __device__ __forceinline__

typedef __attribute__((ext_vector_type(8))) __bf16 bf16x8;
typedef __attribute__((ext_vector_type(8))) short short8;
typedef __attribute__((ext_vector_type(4))) float f32x4;
typedef __attribute__((ext_vector_type(4))) int int4v;
typedef __attribute__((ext_vector_type(4))) unsigned short ushort4v;

// native RTNE f32->bf16 (v_cvt_pk_bf16_f32 on gfx950)
DI short f2bfn(float f) {
  __bf16 b = (__bf16)f;
  short s;
  __builtin_memcpy(&s, &b, 2);
  return s;
}

// Abramowitz-Stegun 7.1.26 erf (max abs err 1.5e-7)
DI float erf_fast(float x) {
  const float ax = fabsf(x);
  const float t = __builtin_amdgcn_rcpf(1.0f + 0.3275911f * ax);
  float p = 1.061405429f;
  p = p * t - 1.453152027f;
  p = p * t + 1.421413741f;
  p = p * t - 0.284496736f;
  p = p * t + 0.254829592f;
  p = p * t;
  const float r = 1.0f - p * __expf(-ax * ax);
  return copysignf(r, x);
}

DI void gload_lds16(const void* g, void* l) {
  __builtin_amdgcn_global_load_lds(
      (const __attribute__((address_space(1))) void*)g,
      (__attribute__((address_space(3))) void*)l, 16, 0, 0);
}

// ---------------- fused weight prep: 6 transposes + 3 bias copies --------
// blocks 0..2303: Wq/Wk/Wv/Wo (24x24 tiles each); 2304..4607: W1 (96x24);
// 4608..6911: W2 (24x96); 6912..6914: bias concat.
__global__ __launch_bounds__(256) void weight_prep(
    const float* __restrict__ Wq, const float* __restrict__ Wk,
    const float* __restrict__ Wv, const float* __restrict__ Wo,
    const float* __restrict__ W1, const float* __restrict__ W2,
    const float* __restrict__ bq, const float* __restrict__ bk,
    const float* __restrict__ bv,
    short* __restrict__ Wtqkv, short* __restrict__ Wto,
    short* __restrict__ Wt1, short* __restrict__ Wt2,
    float* __restrict__ bqkv)
{
  const int id = blockIdx.x, t = threadIdx.x;
  if (id >= 6912) {  // bias copy
    const int j = id - 6912;
    const float* src = j == 0 ? bq : (j == 1 ? bk : bv);
    for (int e = t; e < 768; e += 256) bqkv[j * 768 + e] = src[e];
    return;
  }
  const float* in;
  short* out;
  int K, N, bx, by;
  if (id < 2304) {
    const int w = id / 576, r2 = id % 576;
    bx = r2 % 24; by = r2 / 24; K = 768; N = 768;
    in = (w == 0) ? Wq : (w == 1) ? Wk : (w == 2) ? Wv : Wo;
    out = (w < 3) ? Wtqkv + (size_t)w * 768 * 768 : Wto;
  } else if (id < 4608) {
    const int r2 = id - 2304;
    bx = r2 % 96; by = r2 / 96; K = 768; N = 3072; in = W1; out = Wt1;
  } else {
    const int r2 = id - 4608;
    bx = r2 % 24; by = r2 / 24; K = 3072; N = 768; in = W2; out = Wt2;
  }
  __shared__ float tile[32][33];
  const int tx = t & 31, ty = t >> 5;
  const int n0 = bx * 32, k0 = by * 32;
#pragma unroll
  for (int p = 0; p < 4; ++p)
    tile[ty + p * 8][tx] = in[(size_t)(k0 + ty + p * 8) * N + n0 + tx];
  __syncthreads();
#pragma unroll
  for (int p = 0; p < 4; ++p)
    out[(size_t)(n0 + ty + p * 8) * K + k0 + tx] = f2bfn(tile[tx][ty + p * 8]);
}

// ---------------- layernorm: 1 wave per row of 768, fp32 in, bf16 out ----
__global__ __launch_bounds__(256) void ln_rows(
    const float* __restrict__ x, const float* __restrict__ gw,
    const float* __restrict__ bw, unsigned short* __restrict__ out)
{
  const int wv = threadIdx.x >> 6, ln = threadIdx.x & 63;
  const size_t row = (size_t)blockIdx.x * 4 + wv;
  const float* xr = x + row * 768;
  float4 v[3];
  float s = 0.f, sq = 0.f;
#pragma unroll
  for (int i = 0; i < 3; ++i) {
    v[i] = *(const float4*)(xr + i * 256 + ln * 4);
    s  += v[i].x + v[i].y + v[i].z + v[i].w;
    sq += v[i].x * v[i].x + v[i].y * v[i].y + v[i].z * v[i].z + v[i].w * v[i].w;
  }
#pragma unroll
  for (int msk = 1; msk < 64; msk <<= 1) {
    s  += __shfl_xor(s, msk);
    sq += __shfl_xor(sq, msk);
  }
  const float mean = s * (1.f / 768.f);
  const float var  = sq * (1.f / 768.f) - mean * mean;
  const float rstd = rsqrtf(var + 1e-5f);
#pragma unroll
  for (int i = 0; i < 3; ++i) {
    const int c = i * 256 + ln * 4;
    const float vals[4] = {v[i].x, v[i].y, v[i].z, v[i].w};
    ushort4v o;
#pragma unroll
    for (int j = 0; j < 4; ++j)
      o[j] = (unsigned short)f2bfn((vals[j] - mean) * rstd * gw[c + j] + bw[c + j]);
    *(ushort4v*)(out + row * 768 + c) = o;
  }
}

// ---------------- GEMM v7: C[M,N] = A[M,K] * Bt[N,K]^T + epilogue ---------
// K-loop unchanged (2-deep counted-vmcnt, both-sides chunk-XOR swizzle).
// Epilogue: wave-private 16x68 fp32 LDS bounce, zero barriers.
// EPI_QKV: V-column tiles (col >= 1536) are written TRANSPOSED into vT
// (column-wise slab read, 16-token-contiguous stores) — fuses v_transpose.
enum { EPI_BF16 = 0, EPI_F32_RES = 1, EPI_BF16_GELU = 2, EPI_F32 = 3, EPI_QKV = 4 };

template <int MODE, int BM, int BK, int MW>
__global__ __launch_bounds__(256, MW) void gemm_bt(
    const short* __restrict__ A,    // pitch = K
    const short* __restrict__ Bt,   // pitch = K
    const float* __restrict__ bias,
    const float* __restrict__ resid,  // pitch = ldc (fp32) when used
    void* __restrict__ Cout, short* __restrict__ vTout,
    int ldc, int Ntiles, int K)
{
  constexpr int NCHUNK = BK / 8;
  constexpr int CMASK = NCHUNK - 1;
  constexpr int ABYTES = BM * BK * 2;
  constexpr int STAGE_BYTES = (BM + 128) * BK * 2;
  constexpr int NLA = BM * BK / 8 / 256;
  constexpr int NLB = 128 * BK / 8 / 256;
  constexpr int LOADS = NLA + NLB;
  constexpr int MR = BM / 32;
  constexpr int NKK = BK / 32;
  constexpr int SMEM = 2 * STAGE_BYTES > 4 * 4352 ? 2 * STAGE_BYTES : 4 * 4352;
  __shared__ __align__(16) char smem[SMEM];
  const int t = threadIdx.x;
  const int wv = t >> 6, ln = t & 63;
  const int g = ln >> 4, r = ln & 15;
  const int sw = ((int)blockIdx.x & 7) * ((int)gridDim.x >> 3) + ((int)blockIdx.x >> 3);
  const int bm = sw / Ntiles, bn = sw % Ntiles;
  const int wr = wv >> 1, wc = wv & 1;
  f32x4 acc[MR][4] = {};

  // staging source pointers (pre-swizzled), advanced by BK elems per stage
  const char* aptr[NLA];
  const char* bptr[NLB];
#pragma unroll
  for (int q = 0; q < NLA; ++q) {
    const int p = q * 256 + t;
    const int row = p / NCHUNK, c = (p & CMASK) ^ (row & CMASK);
    aptr[q] = (const char*)(A + (size_t)(bm * BM + row) * K + c * 8);
  }
#pragma unroll
  for (int q = 0; q < NLB; ++q) {
    const int p = q * 256 + t;
    const int row = p / NCHUNK, c = (p & CMASK) ^ (row & CMASK);
    bptr[q] = (const char*)(Bt + (size_t)(bn * 128 + row) * K + c * 8);
  }

  auto stage = [&](int buf) {
    char* as = smem + buf * STAGE_BYTES;
    char* bs = as + ABYTES;
#pragma unroll
    for (int q = 0; q < NLA; ++q) {
      gload_lds16(aptr[q], as + q * 4096 + wv * 1024);
      aptr[q] += BK * 2;
    }
#pragma unroll
    for (int q = 0; q < NLB; ++q) {
      gload_lds16(bptr[q], bs + q * 4096 + wv * 1024);
      bptr[q] += BK * 2;
    }
  };

  const int nk = K / BK;
  stage(0);
  stage(1);
  int cur = 0;
  for (int kt = 0; kt < nk; ++kt) {
    // barrier A: my stage(kt) landed (in-order retire) + all waves ditto
    if (kt + 1 < nk)
      asm volatile("s_waitcnt vmcnt(%0)\n\ts_barrier" :: "n"(LOADS) : "memory");
    else
      asm volatile("s_waitcnt vmcnt(0)\n\ts_barrier" ::: "memory");
    const short* as = (const short*)(smem + cur * STAGE_BYTES);
    const short* bs = as + ABYTES / 2;
    bf16x8 af[MR][NKK], bfr[4][NKK];
#pragma unroll
    for (int m = 0; m < MR; ++m) {
      const int row = wr * (BM / 2) + m * 16 + r;
#pragma unroll
      for (int kk = 0; kk < NKK; ++kk)
        af[m][kk] = *(const bf16x8*)(as + row * BK + (((kk * 4 + g) ^ (row & CMASK)) << 3));
    }
#pragma unroll
    for (int n = 0; n < 4; ++n) {
      const int row = wc * 64 + n * 16 + r;
#pragma unroll
      for (int kk = 0; kk < NKK; ++kk)
        bfr[n][kk] = *(const bf16x8*)(bs + row * BK + (((kk * 4 + g) ^ (row & CMASK)) << 3));
    }
    // MFMAs: compiler interleaves with the ds_reads via partial lgkmcnt
#pragma unroll
    for (int kk = 0; kk < NKK; ++kk)
#pragma unroll
      for (int m = 0; m < MR; ++m)
#pragma unroll
        for (int n = 0; n < 4; ++n)
          acc[m][n] = __builtin_amdgcn_mfma_f32_16x16x32_bf16(af[m][kk], bfr[n][kk],
                                                              acc[m][n], 0, 0, 0);
    if (kt + 2 < nk) {
      // barrier B: my reads complete + all waves done reading buf[cur]
      asm volatile("s_waitcnt lgkmcnt(0)\n\ts_barrier" ::: "memory");
      stage(cur);
    }
    cur ^= 1;
  }
  __syncthreads();  // all waves done with stage buffers before epi overwrite

  // ---- epilogue: wave-private LDS bounce, zero barriers ----
  float* epi = (float*)(smem + wv * 4352);   // 16 x 68 fp32 per wave

  if constexpr (MODE == EPI_QKV) {
    if (bn * 128 >= 1536) {
      // transposed V write: vT[(b*768 + cv)*1024 + tok]
      const int tc = ln;                                // col within 64-strip
      const int cglob = bn * 128 + wc * 64 + tc;
      const int cv = cglob - 1536;
      const float bvs = bias[cglob];
#pragma unroll
      for (int m = 0; m < MR; ++m) {
#pragma unroll
        for (int n = 0; n < 4; ++n)
#pragma unroll
          for (int q = 0; q < 4; ++q)
            epi[(g * 4 + q) * 68 + n * 16 + r] = acc[m][n][q];
        // wave-internal DS ordering; column-wise read (lanes = consecutive
        // dwords per row -> conflict-free)
        float tv[16];
#pragma unroll
        for (int row = 0; row < 16; ++row) tv[row] = epi[row * 68 + tc] + bvs;
        const int tokbase = bm * BM + wr * (BM / 2) + m * 16;
        const int bb = tokbase >> 10, toff = tokbase & 1023;
        short8 o0, o1;
#pragma unroll
        for (int e = 0; e < 8; ++e) { o0[e] = f2bfn(tv[e]); o1[e] = f2bfn(tv[e + 8]); }
        short* dst = vTout + ((size_t)(bb * 768 + cv)) * 1024 + toff;
        *(short8*)dst = o0;
        *(short8*)(dst + 8) = o1;
      }
      return;
    }
  }

  const int cq = (ln & 3) * 16;               // 16-col slice in 64-col strip
  const int lr = ln >> 2;                     // 0..15 row within slab
  const int c0 = bn * 128 + wc * 64 + cq;
  f32x4 bv[4];
#pragma unroll
  for (int j = 0; j < 4; ++j) bv[j] = *(const f32x4*)(bias + c0 + j * 4);

#pragma unroll
  for (int m = 0; m < MR; ++m) {
#pragma unroll
    for (int n = 0; n < 4; ++n)
#pragma unroll
      for (int q = 0; q < 4; ++q)
        epi[(g * 4 + q) * 68 + n * 16 + r] = acc[m][n][q];
    // wave-internal DS ordering: reads below see this wave's writes above
    const size_t grow = (size_t)(bm * BM + wr * (BM / 2) + m * 16 + lr);
    float vals[16];
#pragma unroll
    for (int j = 0; j < 4; ++j) {
      const f32x4 vv = *(const f32x4*)(epi + lr * 68 + cq + j * 4);
#pragma unroll
      for (int e = 0; e < 4; ++e) vals[j * 4 + e] = vv[e] + bv[j][e];
    }
    if constexpr (MODE == EPI_F32_RES) {
#pragma unroll
      for (int j = 0; j < 4; ++j) {
        const f32x4 rv = *(const f32x4*)(resid + grow * ldc + c0 + j * 4);
#pragma unroll
        for (int e = 0; e < 4; ++e) vals[j * 4 + e] += rv[e];
      }
    }
    if constexpr (MODE == EPI_BF16_GELU) {
#pragma unroll
      for (int j = 0; j < 16; ++j)
        vals[j] = 0.5f * vals[j] * (1.0f + erf_fast(vals[j] * 0.70710678118654752f));
    }
    if constexpr (MODE == EPI_F32 || MODE == EPI_F32_RES) {
      float* op = (float*)Cout + grow * ldc + c0;
#pragma unroll
      for (int j = 0; j < 4; ++j) {
        f32x4 ov;
#pragma unroll
        for (int e = 0; e < 4; ++e) ov[e] = vals[j * 4 + e];
        *(f32x4*)(op + j * 4) = ov;
      }
    } else {
      unsigned short* op = (unsigned short*)Cout + grow * ldc + c0;
#pragma unroll
      for (int hhalf = 0; hhalf < 2; ++hhalf) {
        short8 ov;
#pragma unroll
        for (int e = 0; e < 8; ++e) ov[e] = f2bfn(vals[hhalf * 8 + e]);
        *(short8*)(op + hhalf * 8) = ov;
      }
    }
  }
}

// ---------------- flash attention v6: swapped QK^T (lane-major softmax) --
// (unchanged from round 15)
__global__ __launch_bounds__(256, 2) void attn_fwd(
    const short* __restrict__ qkv, const short* __restrict__ vT,
    unsigned short* __restrict__ ab)
{
  __shared__ short Ks[2][64 * 128];    // 32 KB
  __shared__ short Vs[2][96 * 64];     // 24 KB
  __shared__ short Ps[4][2][16 * 64];  // 16 KB
  const int t = threadIdx.x, wv = t >> 6, ln = t & 63;
  const int g = ln >> 4, r = ln & 15;
  const int bid = ((int)blockIdx.x & 7) * 64 + ((int)blockIdx.x >> 3);
  const int bh = bid >> 3, qt = bid & 7;
  const int b = bh >> 3, h = bh & 7;

  bf16x8 qf[2][3];
#pragma unroll
  for (int u = 0; u < 2; ++u) {
    const size_t rowq = (size_t)(b * 1024 + qt * 128 + wv * 32 + u * 16 + r);
#pragma unroll
    for (int kd = 0; kd < 3; ++kd)
      qf[u][kd] = *(const bf16x8*)(qkv + rowq * 2304 + h * 96 + kd * 32 + g * 8);
  }

  size_t offK[4];
#pragma unroll
  for (int i = 0; i < 4; ++i) {
    const int p = i * 256 + t;
    const int row = p >> 4, cb = p & 15, cbs = cb ^ (row & 7);
    offK[i] = (size_t)row * 2304 + 768 + h * 96 + (cbs << 3);
  }
  size_t offV[3];
#pragma unroll
  for (int i = 0; i < 3; ++i) {
    const int p = i * 256 + t;
    const int row = p >> 3, cb = p & 7, cbs = cb ^ (row & 7);
    offV[i] = ((size_t)bh * 96 + row) * 1024 + (cbs << 3);
  }
  const short* qb = qkv + (size_t)b * 1024 * 2304;

  auto stageKV = [&](int buf, int kt) {
    const size_t kadd = (size_t)kt * 64 * 2304;
#pragma unroll
    for (int i = 0; i < 4; ++i)
      gload_lds16(qb + kadd + offK[i], (char*)Ks[buf] + i * 4096 + wv * 1024);
#pragma unroll
    for (int i = 0; i < 3; ++i)
      gload_lds16(vT + offV[i] + kt * 64, (char*)Vs[buf] + i * 4096 + wv * 1024);
  };

  f32x4 o[2][6] = {};
  float mr[2] = {-1e30f, -1e30f}, lr[2] = {0.f, 0.f};  // stats for q-row r

  stageKV(0, 0);
  __syncthreads();
  int cur = 0;
  for (int kt = 0; kt < 16; ++kt) {
    if (kt < 15) stageKV(cur ^ 1, kt + 1);
    const short* ks = Ks[cur];
    const short* vs = Vs[cur];

    // ---- S^T = K Q^T for BOTH u, sharing each kf fragment ----
    f32x4 s[2][4] = {};
    __builtin_amdgcn_s_setprio(1);
#pragma unroll
    for (int sub = 0; sub < 4; ++sub) {
      bf16x8 kf[3];
#pragma unroll
      for (int kd = 0; kd < 3; ++kd)
        kf[kd] = *(const bf16x8*)(
            ks + (sub * 16 + r) * 128 + (((kd * 4 + g) ^ (r & 7)) << 3));
#pragma unroll
      for (int u = 0; u < 2; ++u)
#pragma unroll
        for (int kd = 0; kd < 3; ++kd)
          s[u][sub] = __builtin_amdgcn_mfma_f32_16x16x32_bf16(kf[kd], qf[u][kd],
                                                              s[u][sub], 0, 0, 0);
    }
    __builtin_amdgcn_s_setprio(0);

    // ---- lane-major online softmax per u ----
#pragma unroll
    for (int u = 0; u < 2; ++u) {
      float tm = fmaxf(fmaxf(s[u][0][0], s[u][0][1]),
                       fmaxf(s[u][0][2], s[u][0][3]));
#pragma unroll
      for (int sub = 1; sub < 4; ++sub)
        tm = fmaxf(tm, fmaxf(fmaxf(s[u][sub][0], s[u][sub][1]),
                             fmaxf(s[u][sub][2], s[u][sub][3])));
      tm = fmaxf(tm, __shfl_xor(tm, 16));
      tm = fmaxf(tm, __shfl_xor(tm, 32));

      if (__any(tm > mr[u] + 8.f)) {   // defer-max: rescale rarely
        const float mnew = fmaxf(mr[u], tm);
        const float sc = __expf(mr[u] - mnew);
        lr[u] *= sc;
        mr[u] = mnew;
        float scr[4];
#pragma unroll
        for (int reg = 0; reg < 4; ++reg)
          scr[reg] = __shfl(sc, (ln & 48) | (g * 4 + reg));
#pragma unroll
        for (int nd = 0; nd < 6; ++nd)
#pragma unroll
          for (int reg = 0; reg < 4; ++reg) o[u][nd][reg] *= scr[reg];
      }

      float tsum = 0.f;
#pragma unroll
      for (int sub = 0; sub < 4; ++sub) {
        float p0 = __expf(s[u][sub][0] - mr[u]);
        float p1 = __expf(s[u][sub][1] - mr[u]);
        float p2 = __expf(s[u][sub][2] - mr[u]);
        float p3 = __expf(s[u][sub][3] - mr[u]);
        tsum += (p0 + p1) + (p2 + p3);
        ushort4v pk;
        pk[0] = (unsigned short)f2bfn(p0);
        pk[1] = (unsigned short)f2bfn(p1);
        pk[2] = (unsigned short)f2bfn(p2);
        pk[3] = (unsigned short)f2bfn(p3);
        const int c8 = (sub * 4 + g) ^ ((r & 7) << 1);
        *(ushort4v*)((char*)Ps[wv][u] + r * 128 + c8 * 8) = pk;
      }
      tsum += __shfl_xor(tsum, 16);
      tsum += __shfl_xor(tsum, 32);
      lr[u] += tsum;
    }

    // ---- O += P V for BOTH u, sharing each vf fragment ----
    bf16x8 pf[2][2];
#pragma unroll
    for (int u = 0; u < 2; ++u)
#pragma unroll
      for (int kk = 0; kk < 2; ++kk)
        pf[u][kk] = *(const bf16x8*)(
            Ps[wv][u] + r * 64 + (((kk * 4 + g) ^ (r & 7)) << 3));
    __builtin_amdgcn_s_setprio(1);
#pragma unroll
    for (int nd = 0; nd < 6; ++nd) {
      bf16x8 vf[2];
#pragma unroll
      for (int kk = 0; kk < 2; ++kk)
        vf[kk] = *(const bf16x8*)(
            vs + (nd * 16 + r) * 64 + (((kk * 4 + g) ^ (r & 7)) << 3));
#pragma unroll
      for (int u = 0; u < 2; ++u)
#pragma unroll
        for (int kk = 0; kk < 2; ++kk)
          o[u][nd] = __builtin_amdgcn_mfma_f32_16x16x32_bf16(pf[u][kk], vf[kk],
                                                             o[u][nd], 0, 0, 0);
    }
    __builtin_amdgcn_s_setprio(0);

    __syncthreads();  // drains stage(kt+1); frees cur for rewrite
    cur ^= 1;
  }

  // epilogue: O * (96 / l); l for o-row g*4+reg fetched from lane r'=row
#pragma unroll
  for (int u = 0; u < 2; ++u) {
    float linv[4];
#pragma unroll
    for (int reg = 0; reg < 4; ++reg)
      linv[reg] = 96.0f / __shfl(lr[u], (ln & 48) | (g * 4 + reg));
#pragma unroll
    for (int reg = 0; reg < 4; ++reg) {
      const size_t row = (size_t)(b * 1024 + qt * 128 + wv * 32 + u * 16 + g * 4 + reg);
#pragma unroll
      for (int nd = 0; nd < 6; ++nd)
        ab[row * 768 + h * 96 + nd * 16 + r] =
            (unsigned short)f2bfn(o[u][nd][reg] * linv[reg]);
    }
  }
}

// ------------------------------------------------------------------------
extern "C" void kernel_launch(void* const* d_in, const int* in_sizes, int n_in,
                              void* d_out, int out_size, void* d_ws, size_t ws_size,
                              hipStream_t stream)
{
  const float* x    = (const float*)d_in[0];
  const float* ln1g = (const float*)d_in[1];
  const float* ln1b = (const float*)d_in[2];
  const float* Wq   = (const float*)d_in[3];
  const float* bq   = (const float*)d_in[4];
  const float* Wk   = (const float*)d_in[5];
  const float* bk   = (const float*)d_in[6];
  const float* Wv   = (const float*)d_in[7];
  const float* bv   = (const float*)d_in[8];
  const float* Wo   = (const float*)d_in[9];
  const float* bo   = (const float*)d_in[10];
  const float* ln2g = (const float*)d_in[11];
  const float* ln2b = (const float*)d_in[12];
  const float* W1   = (const float*)d_in[13];
  const float* b1   = (const float*)d_in[14];
  const float* W2   = (const float*)d_in[15];
  const float* b2   = (const float*)d_in[16];

  char* ws = (char*)d_ws;
  size_t off = 0;
  short* Wtqkv = (short*)(ws + off); off += (size_t)2304 * 768 * 2;
  short* Wto   = (short*)(ws + off); off += (size_t)768 * 768 * 2;
  short* Wt1   = (short*)(ws + off); off += (size_t)3072 * 768 * 2;
  short* Wt2   = (short*)(ws + off); off += (size_t)768 * 3072 * 2;
  float* bqkv  = (float*)(ws + off); off += 16384;
  short* hb    = (short*)(ws + off); off += (size_t)8192 * 768 * 2;
  short* qkv   = (short*)(ws + off); off += (size_t)8192 * 2304 * 2;
  short* h2b   = (short*)(ws + off); off += (size_t)8192 * 768 * 2;
  short* f1 = hb;          // [8192][3072] bf16, overlays hb+qkv (both dead)
  short* ab = hb;          // attention output overlays hb
  short* vT = h2b;         // V^T [64*96][1024], overlays h2b
  float* x1 = (float*)d_out;  // residual stream parked in d_out

  // all weight transposes + bias concat in ONE kernel (was 9 launches)
  weight_prep<<<6915, 256, 0, stream>>>(Wq, Wk, Wv, Wo, W1, W2, bq, bk, bv,
                                        Wtqkv, Wto, Wt1, Wt2, bqkv);

  ln_rows<<<2048, 256, 0, stream>>>(x, ln1g, ln1b, (unsigned short*)hb);
  // QKV GEMM with fused V-transpose epilogue (V tiles -> vT directly)
  gemm_bt<EPI_QKV, 128, 32, 4><<<64 * 18, 256, 0, stream>>>(
      hb, Wtqkv, bqkv, nullptr, qkv, vT, 2304, 18, 768);
  attn_fwd<<<512, 256, 0, stream>>>(qkv, vT, (unsigned short*)ab);
  gemm_bt<EPI_F32_RES, 64, 64, 3><<<128 * 6, 256, 0, stream>>>(
      ab, Wto, bo, x, x1, nullptr, 768, 6, 768);

  ln_rows<<<2048, 256, 0, stream>>>(x1, ln2g, ln2b, (unsigned short*)h2b);
  gemm_bt<EPI_BF16_GELU, 128, 32, 4><<<64 * 24, 256, 0, stream>>>(
      h2b, Wt1, b1, nullptr, f1, nullptr, 3072, 24, 768);
  gemm_bt<EPI_F32, 64, 64, 3><<<128 * 6, 256, 0, stream>>>(
      f1, Wt2, b2, nullptr, (float*)d_out, nullptr, 768, 6, 3072);
}

// Round 17
// 240.744 us; speedup vs baseline: 1.1016x; 1.0066x over previous
//
#include <hip/hip_runtime.h>
#include <hip/hip_bf16.h>
#include <math.h>

#define DI __device__ __forceinline__

typedef __attribute__((ext_vector_type(8))) __bf16 bf16x8;
typedef __attribute__((ext_vector_type(8))) short short8;
typedef __attribute__((ext_vector_type(4))) float f32x4;
typedef __attribute__((ext_vector_type(4))) int int4v;
typedef __attribute__((ext_vector_type(4))) unsigned short ushort4v;

// native RTNE f32->bf16 (v_cvt_pk_bf16_f32 on gfx950)
DI short f2bfn(float f) {
  __bf16 b = (__bf16)f;
  short s;
  __builtin_memcpy(&s, &b, 2);
  return s;
}

// Abramowitz-Stegun 7.1.26 erf (max abs err 1.5e-7)
DI float erf_fast(float x) {
  const float ax = fabsf(x);
  const float t = __builtin_amdgcn_rcpf(1.0f + 0.3275911f * ax);
  float p = 1.061405429f;
  p = p * t - 1.453152027f;
  p = p * t + 1.421413741f;
  p = p * t - 0.284496736f;
  p = p * t + 0.254829592f;
  p = p * t;
  const float r = 1.0f - p * __expf(-ax * ax);
  return copysignf(r, x);
}

DI void gload_lds16(const void* g, void* l) {
  __builtin_amdgcn_global_load_lds(
      (const __attribute__((address_space(1))) void*)g,
      (__attribute__((address_space(3))) void*)l, 16, 0, 0);
}

// ---------------- fused weight prep: 6 transposes + 3 bias copies --------
__global__ __launch_bounds__(256) void weight_prep(
    const float* __restrict__ Wq, const float* __restrict__ Wk,
    const float* __restrict__ Wv, const float* __restrict__ Wo,
    const float* __restrict__ W1, const float* __restrict__ W2,
    const float* __restrict__ bq, const float* __restrict__ bk,
    const float* __restrict__ bv,
    short* __restrict__ Wtqkv, short* __restrict__ Wto,
    short* __restrict__ Wt1, short* __restrict__ Wt2,
    float* __restrict__ bqkv)
{
  const int id = blockIdx.x, t = threadIdx.x;
  if (id >= 6912) {  // bias copy
    const int j = id - 6912;
    const float* src = j == 0 ? bq : (j == 1 ? bk : bv);
    for (int e = t; e < 768; e += 256) bqkv[j * 768 + e] = src[e];
    return;
  }
  const float* in;
  short* out;
  int K, N, bx, by;
  if (id < 2304) {
    const int w = id / 576, r2 = id % 576;
    bx = r2 % 24; by = r2 / 24; K = 768; N = 768;
    in = (w == 0) ? Wq : (w == 1) ? Wk : (w == 2) ? Wv : Wo;
    out = (w < 3) ? Wtqkv + (size_t)w * 768 * 768 : Wto;
  } else if (id < 4608) {
    const int r2 = id - 2304;
    bx = r2 % 96; by = r2 / 96; K = 768; N = 3072; in = W1; out = Wt1;
  } else {
    const int r2 = id - 4608;
    bx = r2 % 24; by = r2 / 24; K = 3072; N = 768; in = W2; out = Wt2;
  }
  __shared__ float tile[32][33];
  const int tx = t & 31, ty = t >> 5;
  const int n0 = bx * 32, k0 = by * 32;
#pragma unroll
  for (int p = 0; p < 4; ++p)
    tile[ty + p * 8][tx] = in[(size_t)(k0 + ty + p * 8) * N + n0 + tx];
  __syncthreads();
#pragma unroll
  for (int p = 0; p < 4; ++p)
    out[(size_t)(n0 + ty + p * 8) * K + k0 + tx] = f2bfn(tile[tx][ty + p * 8]);
}

// ---------------- layernorm: 1 wave per row of 768, fp32 in, bf16 out ----
__global__ __launch_bounds__(256) void ln_rows(
    const float* __restrict__ x, const float* __restrict__ gw,
    const float* __restrict__ bw, unsigned short* __restrict__ out)
{
  const int wv = threadIdx.x >> 6, ln = threadIdx.x & 63;
  const size_t row = (size_t)blockIdx.x * 4 + wv;
  const float* xr = x + row * 768;
  float4 v[3];
  float s = 0.f, sq = 0.f;
#pragma unroll
  for (int i = 0; i < 3; ++i) {
    v[i] = *(const float4*)(xr + i * 256 + ln * 4);
    s  += v[i].x + v[i].y + v[i].z + v[i].w;
    sq += v[i].x * v[i].x + v[i].y * v[i].y + v[i].z * v[i].z + v[i].w * v[i].w;
  }
#pragma unroll
  for (int msk = 1; msk < 64; msk <<= 1) {
    s  += __shfl_xor(s, msk);
    sq += __shfl_xor(sq, msk);
  }
  const float mean = s * (1.f / 768.f);
  const float var  = sq * (1.f / 768.f) - mean * mean;
  const float rstd = rsqrtf(var + 1e-5f);
#pragma unroll
  for (int i = 0; i < 3; ++i) {
    const int c = i * 256 + ln * 4;
    const float vals[4] = {v[i].x, v[i].y, v[i].z, v[i].w};
    ushort4v o;
#pragma unroll
    for (int j = 0; j < 4; ++j)
      o[j] = (unsigned short)f2bfn((vals[j] - mean) * rstd * gw[c + j] + bw[c + j]);
    *(ushort4v*)(out + row * 768 + c) = o;
  }
}

// ---------------- GEMM v8: C[M,N] = A[M,K] * Bt[N,K]^T + epilogue ---------
// NBUF=3 (QKV/FFN1): 3-buffer rotation -> barrier B ELIMINATED (1 barrier
//   per K-step). Proof: in body kt every wave's reads of buf[kt%3] complete
//   before its MFMAs issue (register deps force lgkmcnt), hence before
//   barrier A of kt+1; the overwrite (stage kt+2 -> buf[(kt-1)%3]) issues
//   only after barrier A of kt. Barrier A separates all reads from the
//   overwrite. Counted vmcnt unchanged (in-order vmem retire).
// NBUF=2 (O-proj/FFN2, BK=64): round-15 two-barrier structure kept.
// Epilogue: wave-private 16x68 fp32 LDS bounce, zero barriers; fast-erf
// GELU; EPI_QKV writes V tiles transposed into vT (fused v_transpose).
enum { EPI_BF16 = 0, EPI_F32_RES = 1, EPI_BF16_GELU = 2, EPI_F32 = 3, EPI_QKV = 4 };

template <int MODE, int BM, int BK, int MW, int NBUF>
__global__ __launch_bounds__(256, MW) void gemm_bt(
    const short* __restrict__ A,    // pitch = K
    const short* __restrict__ Bt,   // pitch = K
    const float* __restrict__ bias,
    const float* __restrict__ resid,  // pitch = ldc (fp32) when used
    void* __restrict__ Cout, short* __restrict__ vTout,
    int ldc, int Ntiles, int K)
{
  constexpr int NCHUNK = BK / 8;
  constexpr int CMASK = NCHUNK - 1;
  constexpr int ABYTES = BM * BK * 2;
  constexpr int STAGE_BYTES = (BM + 128) * BK * 2;
  constexpr int NLA = BM * BK / 8 / 256;
  constexpr int NLB = 128 * BK / 8 / 256;
  constexpr int LOADS = NLA + NLB;
  constexpr int MR = BM / 32;
  constexpr int NKK = BK / 32;
  constexpr int SMEM = NBUF * STAGE_BYTES > 4 * 4352 ? NBUF * STAGE_BYTES
                                                     : 4 * 4352;
  __shared__ __align__(16) char smem[SMEM];
  const int t = threadIdx.x;
  const int wv = t >> 6, ln = t & 63;
  const int g = ln >> 4, r = ln & 15;
  const int sw = ((int)blockIdx.x & 7) * ((int)gridDim.x >> 3) + ((int)blockIdx.x >> 3);
  const int bm = sw / Ntiles, bn = sw % Ntiles;
  const int wr = wv >> 1, wc = wv & 1;
  f32x4 acc[MR][4] = {};

  // staging source pointers (pre-swizzled), advanced by BK elems per stage
  const char* aptr[NLA];
  const char* bptr[NLB];
#pragma unroll
  for (int q = 0; q < NLA; ++q) {
    const int p = q * 256 + t;
    const int row = p / NCHUNK, c = (p & CMASK) ^ (row & CMASK);
    aptr[q] = (const char*)(A + (size_t)(bm * BM + row) * K + c * 8);
  }
#pragma unroll
  for (int q = 0; q < NLB; ++q) {
    const int p = q * 256 + t;
    const int row = p / NCHUNK, c = (p & CMASK) ^ (row & CMASK);
    bptr[q] = (const char*)(Bt + (size_t)(bn * 128 + row) * K + c * 8);
  }

  auto stage = [&](int buf) {
    char* as = smem + buf * STAGE_BYTES;
    char* bs = as + ABYTES;
#pragma unroll
    for (int q = 0; q < NLA; ++q) {
      gload_lds16(aptr[q], as + q * 4096 + wv * 1024);
      aptr[q] += BK * 2;
    }
#pragma unroll
    for (int q = 0; q < NLB; ++q) {
      gload_lds16(bptr[q], bs + q * 4096 + wv * 1024);
      bptr[q] += BK * 2;
    }
  };

  const int nk = K / BK;
  stage(0);
  stage(1);
  int rb = 0;   // read-buffer index
  for (int kt = 0; kt < nk; ++kt) {
    // barrier A: my stage(kt) landed (in-order retire) + all waves ditto
    if (kt + 1 < nk)
      asm volatile("s_waitcnt vmcnt(%0)\n\ts_barrier" :: "n"(LOADS) : "memory");
    else
      asm volatile("s_waitcnt vmcnt(0)\n\ts_barrier" ::: "memory");
    const short* as = (const short*)(smem + rb * STAGE_BYTES);
    const short* bs = as + ABYTES / 2;
    bf16x8 af[MR][NKK], bfr[4][NKK];
#pragma unroll
    for (int m = 0; m < MR; ++m) {
      const int row = wr * (BM / 2) + m * 16 + r;
#pragma unroll
      for (int kk = 0; kk < NKK; ++kk)
        af[m][kk] = *(const bf16x8*)(as + row * BK + (((kk * 4 + g) ^ (row & CMASK)) << 3));
    }
#pragma unroll
    for (int n = 0; n < 4; ++n) {
      const int row = wc * 64 + n * 16 + r;
#pragma unroll
      for (int kk = 0; kk < NKK; ++kk)
        bfr[n][kk] = *(const bf16x8*)(bs + row * BK + (((kk * 4 + g) ^ (row & CMASK)) << 3));
    }
    if constexpr (NBUF == 3) {
      // issue next-next stage NOW (targets buf nobody reads; hides under MFMAs)
      if (kt + 2 < nk) {
        int sb = rb + 2; if (sb >= 3) sb -= 3;
        stage(sb);
      }
#pragma unroll
      for (int kk = 0; kk < NKK; ++kk)
#pragma unroll
        for (int m = 0; m < MR; ++m)
#pragma unroll
          for (int n = 0; n < 4; ++n)
            acc[m][n] = __builtin_amdgcn_mfma_f32_16x16x32_bf16(af[m][kk], bfr[n][kk],
                                                                acc[m][n], 0, 0, 0);
      rb = rb == 2 ? 0 : rb + 1;
    } else {
#pragma unroll
      for (int kk = 0; kk < NKK; ++kk)
#pragma unroll
        for (int m = 0; m < MR; ++m)
#pragma unroll
          for (int n = 0; n < 4; ++n)
            acc[m][n] = __builtin_amdgcn_mfma_f32_16x16x32_bf16(af[m][kk], bfr[n][kk],
                                                                acc[m][n], 0, 0, 0);
      if (kt + 2 < nk) {
        // barrier B: my reads complete + all waves done reading buf[rb]
        asm volatile("s_waitcnt lgkmcnt(0)\n\ts_barrier" ::: "memory");
        stage(rb);
      }
      rb ^= 1;
    }
  }
  __syncthreads();  // all waves done with stage buffers before epi overwrite

  // ---- epilogue: wave-private LDS bounce, zero barriers ----
  float* epi = (float*)(smem + wv * 4352);   // 16 x 68 fp32 per wave

  if constexpr (MODE == EPI_QKV) {
    if (bn * 128 >= 1536) {
      // transposed V write: vT[(b*768 + cv)*1024 + tok]
      const int tc = ln;                                // col within 64-strip
      const int cglob = bn * 128 + wc * 64 + tc;
      const int cv = cglob - 1536;
      const float bvs = bias[cglob];
#pragma unroll
      for (int m = 0; m < MR; ++m) {
#pragma unroll
        for (int n = 0; n < 4; ++n)
#pragma unroll
          for (int q = 0; q < 4; ++q)
            epi[(g * 4 + q) * 68 + n * 16 + r] = acc[m][n][q];
        float tv[16];
#pragma unroll
        for (int row = 0; row < 16; ++row) tv[row] = epi[row * 68 + tc] + bvs;
        const int tokbase = bm * BM + wr * (BM / 2) + m * 16;
        const int bb = tokbase >> 10, toff = tokbase & 1023;
        short8 o0, o1;
#pragma unroll
        for (int e = 0; e < 8; ++e) { o0[e] = f2bfn(tv[e]); o1[e] = f2bfn(tv[e + 8]); }
        short* dst = vTout + ((size_t)(bb * 768 + cv)) * 1024 + toff;
        *(short8*)dst = o0;
        *(short8*)(dst + 8) = o1;
      }
      return;
    }
  }

  const int cq = (ln & 3) * 16;               // 16-col slice in 64-col strip
  const int lr = ln >> 2;                     // 0..15 row within slab
  const int c0 = bn * 128 + wc * 64 + cq;
  f32x4 bv[4];
#pragma unroll
  for (int j = 0; j < 4; ++j) bv[j] = *(const f32x4*)(bias + c0 + j * 4);

#pragma unroll
  for (int m = 0; m < MR; ++m) {
#pragma unroll
    for (int n = 0; n < 4; ++n)
#pragma unroll
      for (int q = 0; q < 4; ++q)
        epi[(g * 4 + q) * 68 + n * 16 + r] = acc[m][n][q];
    // wave-internal DS ordering: reads below see this wave's writes above
    const size_t grow = (size_t)(bm * BM + wr * (BM / 2) + m * 16 + lr);
    float vals[16];
#pragma unroll
    for (int j = 0; j < 4; ++j) {
      const f32x4 vv = *(const f32x4*)(epi + lr * 68 + cq + j * 4);
#pragma unroll
      for (int e = 0; e < 4; ++e) vals[j * 4 + e] = vv[e] + bv[j][e];
    }
    if constexpr (MODE == EPI_F32_RES) {
#pragma unroll
      for (int j = 0; j < 4; ++j) {
        const f32x4 rv = *(const f32x4*)(resid + grow * ldc + c0 + j * 4);
#pragma unroll
        for (int e = 0; e < 4; ++e) vals[j * 4 + e] += rv[e];
      }
    }
    if constexpr (MODE == EPI_BF16_GELU) {
#pragma unroll
      for (int j = 0; j < 16; ++j)
        vals[j] = 0.5f * vals[j] * (1.0f + erf_fast(vals[j] * 0.70710678118654752f));
    }
    if constexpr (MODE == EPI_F32 || MODE == EPI_F32_RES) {
      float* op = (float*)Cout + grow * ldc + c0;
#pragma unroll
      for (int j = 0; j < 4; ++j) {
        f32x4 ov;
#pragma unroll
        for (int e = 0; e < 4; ++e) ov[e] = vals[j * 4 + e];
        *(f32x4*)(op + j * 4) = ov;
      }
    } else {
      unsigned short* op = (unsigned short*)Cout + grow * ldc + c0;
#pragma unroll
      for (int hhalf = 0; hhalf < 2; ++hhalf) {
        short8 ov;
#pragma unroll
        for (int e = 0; e < 8; ++e) ov[e] = f2bfn(vals[hhalf * 8 + e]);
        *(short8*)(op + hhalf * 8) = ov;
      }
    }
  }
}

// ---------------- flash attention v6: swapped QK^T (lane-major softmax) --
// (unchanged from round 16)
__global__ __launch_bounds__(256, 2) void attn_fwd(
    const short* __restrict__ qkv, const short* __restrict__ vT,
    unsigned short* __restrict__ ab)
{
  __shared__ short Ks[2][64 * 128];    // 32 KB
  __shared__ short Vs[2][96 * 64];     // 24 KB
  __shared__ short Ps[4][2][16 * 64];  // 16 KB
  const int t = threadIdx.x, wv = t >> 6, ln = t & 63;
  const int g = ln >> 4, r = ln & 15;
  const int bid = ((int)blockIdx.x & 7) * 64 + ((int)blockIdx.x >> 3);
  const int bh = bid >> 3, qt = bid & 7;
  const int b = bh >> 3, h = bh & 7;

  bf16x8 qf[2][3];
#pragma unroll
  for (int u = 0; u < 2; ++u) {
    const size_t rowq = (size_t)(b * 1024 + qt * 128 + wv * 32 + u * 16 + r);
#pragma unroll
    for (int kd = 0; kd < 3; ++kd)
      qf[u][kd] = *(const bf16x8*)(qkv + rowq * 2304 + h * 96 + kd * 32 + g * 8);
  }

  size_t offK[4];
#pragma unroll
  for (int i = 0; i < 4; ++i) {
    const int p = i * 256 + t;
    const int row = p >> 4, cb = p & 15, cbs = cb ^ (row & 7);
    offK[i] = (size_t)row * 2304 + 768 + h * 96 + (cbs << 3);
  }
  size_t offV[3];
#pragma unroll
  for (int i = 0; i < 3; ++i) {
    const int p = i * 256 + t;
    const int row = p >> 3, cb = p & 7, cbs = cb ^ (row & 7);
    offV[i] = ((size_t)bh * 96 + row) * 1024 + (cbs << 3);
  }
  const short* qb = qkv + (size_t)b * 1024 * 2304;

  auto stageKV = [&](int buf, int kt) {
    const size_t kadd = (size_t)kt * 64 * 2304;
#pragma unroll
    for (int i = 0; i < 4; ++i)
      gload_lds16(qb + kadd + offK[i], (char*)Ks[buf] + i * 4096 + wv * 1024);
#pragma unroll
    for (int i = 0; i < 3; ++i)
      gload_lds16(vT + offV[i] + kt * 64, (char*)Vs[buf] + i * 4096 + wv * 1024);
  };

  f32x4 o[2][6] = {};
  float mr[2] = {-1e30f, -1e30f}, lr[2] = {0.f, 0.f};  // stats for q-row r

  stageKV(0, 0);
  __syncthreads();
  int cur = 0;
  for (int kt = 0; kt < 16; ++kt) {
    if (kt < 15) stageKV(cur ^ 1, kt + 1);
    const short* ks = Ks[cur];
    const short* vs = Vs[cur];

    // ---- S^T = K Q^T for BOTH u, sharing each kf fragment ----
    f32x4 s[2][4] = {};
    __builtin_amdgcn_s_setprio(1);
#pragma unroll
    for (int sub = 0; sub < 4; ++sub) {
      bf16x8 kf[3];
#pragma unroll
      for (int kd = 0; kd < 3; ++kd)
        kf[kd] = *(const bf16x8*)(
            ks + (sub * 16 + r) * 128 + (((kd * 4 + g) ^ (r & 7)) << 3));
#pragma unroll
      for (int u = 0; u < 2; ++u)
#pragma unroll
        for (int kd = 0; kd < 3; ++kd)
          s[u][sub] = __builtin_amdgcn_mfma_f32_16x16x32_bf16(kf[kd], qf[u][kd],
                                                              s[u][sub], 0, 0, 0);
    }
    __builtin_amdgcn_s_setprio(0);

    // ---- lane-major online softmax per u ----
#pragma unroll
    for (int u = 0; u < 2; ++u) {
      float tm = fmaxf(fmaxf(s[u][0][0], s[u][0][1]),
                       fmaxf(s[u][0][2], s[u][0][3]));
#pragma unroll
      for (int sub = 1; sub < 4; ++sub)
        tm = fmaxf(tm, fmaxf(fmaxf(s[u][sub][0], s[u][sub][1]),
                             fmaxf(s[u][sub][2], s[u][sub][3])));
      tm = fmaxf(tm, __shfl_xor(tm, 16));
      tm = fmaxf(tm, __shfl_xor(tm, 32));

      if (__any(tm > mr[u] + 8.f)) {   // defer-max: rescale rarely
        const float mnew = fmaxf(mr[u], tm);
        const float sc = __expf(mr[u] - mnew);
        lr[u] *= sc;
        mr[u] = mnew;
        float scr[4];
#pragma unroll
        for (int reg = 0; reg < 4; ++reg)
          scr[reg] = __shfl(sc, (ln & 48) | (g * 4 + reg));
#pragma unroll
        for (int nd = 0; nd < 6; ++nd)
#pragma unroll
          for (int reg = 0; reg < 4; ++reg) o[u][nd][reg] *= scr[reg];
      }

      float tsum = 0.f;
#pragma unroll
      for (int sub = 0; sub < 4; ++sub) {
        float p0 = __expf(s[u][sub][0] - mr[u]);
        float p1 = __expf(s[u][sub][1] - mr[u]);
        float p2 = __expf(s[u][sub][2] - mr[u]);
        float p3 = __expf(s[u][sub][3] - mr[u]);
        tsum += (p0 + p1) + (p2 + p3);
        ushort4v pk;
        pk[0] = (unsigned short)f2bfn(p0);
        pk[1] = (unsigned short)f2bfn(p1);
        pk[2] = (unsigned short)f2bfn(p2);
        pk[3] = (unsigned short)f2bfn(p3);
        const int c8 = (sub * 4 + g) ^ ((r & 7) << 1);
        *(ushort4v*)((char*)Ps[wv][u] + r * 128 + c8 * 8) = pk;
      }
      tsum += __shfl_xor(tsum, 16);
      tsum += __shfl_xor(tsum, 32);
      lr[u] += tsum;
    }

    // ---- O += P V for BOTH u, sharing each vf fragment ----
    bf16x8 pf[2][2];
#pragma unroll
    for (int u = 0; u < 2; ++u)
#pragma unroll
      for (int kk = 0; kk < 2; ++kk)
        pf[u][kk] = *(const bf16x8*)(
            Ps[wv][u] + r * 64 + (((kk * 4 + g) ^ (r & 7)) << 3));
    __builtin_amdgcn_s_setprio(1);
#pragma unroll
    for (int nd = 0; nd < 6; ++nd) {
      bf16x8 vf[2];
#pragma unroll
      for (int kk = 0; kk < 2; ++kk)
        vf[kk] = *(const bf16x8*)(
            vs + (nd * 16 + r) * 64 + (((kk * 4 + g) ^ (r & 7)) << 3));
#pragma unroll
      for (int u = 0; u < 2; ++u)
#pragma unroll
        for (int kk = 0; kk < 2; ++kk)
          o[u][nd] = __builtin_amdgcn_mfma_f32_16x16x32_bf16(pf[u][kk], vf[kk],
                                                             o[u][nd], 0, 0, 0);
    }
    __builtin_amdgcn_s_setprio(0);

    __syncthreads();  // drains stage(kt+1); frees cur for rewrite
    cur ^= 1;
  }

  // epilogue: O * (96 / l); l for o-row g*4+reg fetched from lane r'=row
#pragma unroll
  for (int u = 0; u < 2; ++u) {
    float linv[4];
#pragma unroll
    for (int reg = 0; reg < 4; ++reg)
      linv[reg] = 96.0f / __shfl(lr[u], (ln & 48) | (g * 4 + reg));
#pragma unroll
    for (int reg = 0; reg < 4; ++reg) {
      const size_t row = (size_t)(b * 1024 + qt * 128 + wv * 32 + u * 16 + g * 4 + reg);
#pragma unroll
      for (int nd = 0; nd < 6; ++nd)
        ab[row * 768 + h * 96 + nd * 16 + r] =
            (unsigned short)f2bfn(o[u][nd][reg] * linv[reg]);
    }
  }
}

// ------------------------------------------------------------------------
extern "C" void kernel_launch(void* const* d_in, const int* in_sizes, int n_in,
                              void* d_out, int out_size, void* d_ws, size_t ws_size,
                              hipStream_t stream)
{
  const float* x    = (const float*)d_in[0];
  const float* ln1g = (const float*)d_in[1];
  const float* ln1b = (const float*)d_in[2];
  const float* Wq   = (const float*)d_in[3];
  const float* bq   = (const float*)d_in[4];
  const float* Wk   = (const float*)d_in[5];
  const float* bk   = (const float*)d_in[6];
  const float* Wv   = (const float*)d_in[7];
  const float* bv   = (const float*)d_in[8];
  const float* Wo   = (const float*)d_in[9];
  const float* bo   = (const float*)d_in[10];
  const float* ln2g = (const float*)d_in[11];
  const float* ln2b = (const float*)d_in[12];
  const float* W1   = (const float*)d_in[13];
  const float* b1   = (const float*)d_in[14];
  const float* W2   = (const float*)d_in[15];
  const float* b2   = (const float*)d_in[16];

  char* ws = (char*)d_ws;
  size_t off = 0;
  short* Wtqkv = (short*)(ws + off); off += (size_t)2304 * 768 * 2;
  short* Wto   = (short*)(ws + off); off += (size_t)768 * 768 * 2;
  short* Wt1   = (short*)(ws + off); off += (size_t)3072 * 768 * 2;
  short* Wt2   = (short*)(ws + off); off += (size_t)768 * 3072 * 2;
  float* bqkv  = (float*)(ws + off); off += 16384;
  short* hb    = (short*)(ws + off); off += (size_t)8192 * 768 * 2;
  short* qkv   = (short*)(ws + off); off += (size_t)8192 * 2304 * 2;
  short* h2b   = (short*)(ws + off); off += (size_t)8192 * 768 * 2;
  short* f1 = hb;          // [8192][3072] bf16, overlays hb+qkv (both dead)
  short* ab = hb;          // attention output overlays hb
  short* vT = h2b;         // V^T [64*96][1024], overlays h2b
  float* x1 = (float*)d_out;  // residual stream parked in d_out

  // all weight transposes + bias concat in ONE kernel
  weight_prep<<<6915, 256, 0, stream>>>(Wq, Wk, Wv, Wo, W1, W2, bq, bk, bv,
                                        Wtqkv, Wto, Wt1, Wt2, bqkv);

  ln_rows<<<2048, 256, 0, stream>>>(x, ln1g, ln1b, (unsigned short*)hb);
  // QKV GEMM with fused V-transpose epilogue; 3-buffer single-barrier loop
  gemm_bt<EPI_QKV, 128, 32, 3, 3><<<64 * 18, 256, 0, stream>>>(
      hb, Wtqkv, bqkv, nullptr, qkv, vT, 2304, 18, 768);
  attn_fwd<<<512, 256, 0, stream>>>(qkv, vT, (unsigned short*)ab);
  gemm_bt<EPI_F32_RES, 64, 64, 3, 2><<<128 * 6, 256, 0, stream>>>(
      ab, Wto, bo, x, x1, nullptr, 768, 6, 768);

  ln_rows<<<2048, 256, 0, stream>>>(x1, ln2g, ln2b, (unsigned short*)h2b);
  gemm_bt<EPI_BF16_GELU, 128, 32, 3, 3><<<64 * 24, 256, 0, stream>>>(
      h2b, Wt1, b1, nullptr, f1, nullptr, 3072, 24, 768);
  gemm_bt<EPI_F32, 64, 64, 3, 2><<<128 * 6, 256, 0, stream>>>(
      f1, Wt2, b2, nullptr, (float*)d_out, nullptr, 768, 6, 3072);
}